// Round 9
// baseline (506.591 us; speedup 1.0000x reference)
//
#include <hip/hip_runtime.h>
#include <hip/hip_cooperative_groups.h>

namespace cg = cooperative_groups;

#define N_NODES 50000
#define N_EDGES 800000
#define D_IN 128
#define HIDDEN 64
#define N_CLASSES 2
#define NBUK 782        // ceil(50000/64) buckets of 64 nodes
#define NBUK_P 784      // padded stride (bhist rows)
#define NBLK 782        // edge-chunk blocks: 782*256 threads * 4 edges >= 800000
#define NBLK_P 784      // padded stride (excT rows)

typedef _Float16 half4v __attribute__((ext_vector_type(4)));

// ================= fused CSR build: hist -> colscan -> offset scan -> bin -> bucket CSR ========
// One cooperative launch, 782 blocks x 256 threads; grid.sync() between phases.
// dst4 records persist in registers from phase 1 to phase 4 (saves a 3.2 MB re-read).

__global__ __launch_bounds__(256) void k_csr_build(
    const int4* __restrict__ src4, const int4* __restrict__ dst4,
    int* __restrict__ bhist, int* __restrict__ excT, int* __restrict__ colsum,
    int* __restrict__ bucket_off, int* __restrict__ row_ptr,
    float* __restrict__ dinv, int* __restrict__ ebin, int* __restrict__ rec)
{
    cg::grid_group grid = cg::this_grid();
    __shared__ int sh[NBUK];   // reused: hist / scan partials / cursors
    const int b = blockIdx.x;
    const int t = threadIdx.x;
    const int idx = b * 256 + t;
    const bool valid = idx < N_EDGES / 4;

    // ---- phase 1: per-chunk histogram over dst buckets ----
    for (int i = t; i < NBUK; i += 256) sh[i] = 0;
    __syncthreads();
    int4 d = make_int4(0, 0, 0, 0);
    if (valid) {
        d = dst4[idx];
        atomicAdd(&sh[d.x >> 6], 1);
        atomicAdd(&sh[d.y >> 6], 1);
        atomicAdd(&sh[d.z >> 6], 1);
        atomicAdd(&sh[d.w >> 6], 1);
    }
    __syncthreads();
    for (int i = t; i < NBUK; i += 256) bhist[b * NBUK_P + i] = sh[i];
    grid.sync();

    // ---- phase 2: column scan for bucket b over all chunks; write excT (coalesced) ----
    {
        int v[4];
        int s = 0;
#pragma unroll
        for (int i = 0; i < 4; i++) {
            int blk = t * 4 + i;
            v[i] = (blk < NBLK) ? bhist[blk * NBUK_P + b] : 0;
            s += v[i];
        }
        sh[t] = s;
        __syncthreads();
        for (int off = 1; off < 256; off <<= 1) {
            int p = (t >= off) ? sh[t - off] : 0;
            __syncthreads();
            sh[t] += p;
            __syncthreads();
        }
        int run = (t == 0) ? 0 : sh[t - 1];
#pragma unroll
        for (int i = 0; i < 4; i++) {
            int blk = t * 4 + i;
            if (blk < NBLK) excT[b * NBLK_P + blk] = run;
            run += v[i];
        }
        if (t == 255) colsum[b] = run;
    }
    grid.sync();

    // ---- phase 3: scan 782 bucket totals -> bucket_off (block 0 only) ----
    if (b == 0) {
        int v[4];
        int s = 0;
#pragma unroll
        for (int i = 0; i < 4; i++) {
            int j = t * 4 + i;
            v[i] = (j < NBUK) ? colsum[j] : 0;
            s += v[i];
        }
        sh[t] = s;
        __syncthreads();
        for (int off = 1; off < 256; off <<= 1) {
            int p = (t >= off) ? sh[t - off] : 0;
            __syncthreads();
            sh[t] += p;
            __syncthreads();
        }
        int run = (t == 0) ? 0 : sh[t - 1];
#pragma unroll
        for (int i = 0; i < 4; i++) {
            int j = t * 4 + i;
            if (j < NBUK) { bucket_off[j] = run; run += v[i]; }
            else if (j == NBUK) bucket_off[j] = run;  // == N_EDGES
        }
        if (t == 0) row_ptr[N_NODES] = N_EDGES;
    }
    grid.sync();

    // ---- phase 4: deterministic scatter of packed records (dst in regs from phase 1) ----
    for (int i = t; i < NBUK; i += 256)
        sh[i] = bucket_off[i] + excT[i * NBLK_P + b];
    __syncthreads();
    if (valid) {
        int4 s = src4[idx];
        int p0 = atomicAdd(&sh[d.x >> 6], 1);
        int p1 = atomicAdd(&sh[d.y >> 6], 1);
        int p2 = atomicAdd(&sh[d.z >> 6], 1);
        int p3 = atomicAdd(&sh[d.w >> 6], 1);
        ebin[p0] = (s.x << 7) | (d.x & 63);
        ebin[p1] = (s.y << 7) | (d.y & 63);
        ebin[p2] = (s.z << 7) | (d.z & 63);
        ebin[p3] = (s.w << 7) | (d.w & 63);
    }
    grid.sync();

    // ---- phase 5: per-bucket degree count + scan + node-sorted scatter ----
    {
        if (t < 64) sh[t] = 0;
        __syncthreads();
        int beg = bucket_off[b], end = bucket_off[b + 1];
        for (int i = beg + t; i < end; i += 256) atomicAdd(&sh[ebin[i] & 63], 1);
        __syncthreads();
        if (t < 64) {
            int deg = sh[t];
            int sum = deg;  // inclusive scan over lanes 0..63 (wave 0)
#pragma unroll
            for (int off = 1; off < 64; off <<= 1) {
                int v = __shfl_up(sum, off, 64);
                if (t >= off) sum += v;
            }
            int rp = beg + sum - deg;
            sh[64 + t] = rp;
            int node = b * 64 + t;
            if (node < N_NODES) {
                row_ptr[node] = rp;
                dinv[node] = rsqrtf((float)(deg + 1));  // +1 self-loop
            }
        }
        __syncthreads();
        for (int i = beg + t; i < end; i += 256) {
            int pk = ebin[i];
            int pos = atomicAdd(&sh[64 + (pk & 63)], 1);
            rec[pos] = pk >> 7;
        }
    }
}

// ---------------- GEMM1: hs = (x @ W1) * dinv[row], fp16; pad rows zeroed ----------------

__device__ inline void fma4(float4& acc, float s, const float4& w) {
    acc.x = fmaf(s, w.x, acc.x);
    acc.y = fmaf(s, w.y, acc.y);
    acc.z = fmaf(s, w.z, acc.z);
    acc.w = fmaf(s, w.w, acc.w);
}

__global__ __launch_bounds__(256) void k_gemm1(
    const float* __restrict__ x, const float* __restrict__ W1,
    const float* __restrict__ dinv, _Float16* __restrict__ hs)
{
    __shared__ float Ws[D_IN * HIDDEN];  // 32KB
    __shared__ float xs[64 * D_IN];      // 32KB
    const int tid = threadIdx.x;
    const int row0 = blockIdx.x * 64;

    const float4* W4 = (const float4*)W1;
    float4* Ws4 = (float4*)Ws;
    for (int i = tid; i < D_IN * HIDDEN / 4; i += 256) Ws4[i] = W4[i];

    for (int i = tid; i < 64 * D_IN / 4; i += 256) {
        int r = i >> 5;
        int k4 = (i & 31) << 2;
        float4 v = make_float4(0.f, 0.f, 0.f, 0.f);
        int grow = row0 + r;
        if (grow < N_NODES) v = *(const float4*)&x[grow * D_IN + k4];
        int sw = ((r >> 2) & 1) << 4;
        *(float4*)&xs[r * D_IN + (k4 ^ sw)] = v;
    }
    __syncthreads();

    const int c4 = (tid & 15) * 4;
    const int r4 = (tid >> 4) * 4;
    float4 acc[4];
#pragma unroll
    for (int j = 0; j < 4; j++) acc[j] = make_float4(0.f, 0.f, 0.f, 0.f);

    for (int k = 0; k < D_IN; k += 4) {
        float4 w0 = *(const float4*)&Ws[(k + 0) * HIDDEN + c4];
        float4 w1 = *(const float4*)&Ws[(k + 1) * HIDDEN + c4];
        float4 w2 = *(const float4*)&Ws[(k + 2) * HIDDEN + c4];
        float4 w3 = *(const float4*)&Ws[(k + 3) * HIDDEN + c4];
        float4 a[4];
#pragma unroll
        for (int j = 0; j < 4; j++) {
            int r = r4 + j;
            int sw = ((r >> 2) & 1) << 4;
            a[j] = *(const float4*)&xs[r * D_IN + (k ^ sw)];
        }
#pragma unroll
        for (int j = 0; j < 4; j++) {
            fma4(acc[j], a[j].x, w0);
            fma4(acc[j], a[j].y, w1);
            fma4(acc[j], a[j].z, w2);
            fma4(acc[j], a[j].w, w3);
        }
    }

#pragma unroll
    for (int j = 0; j < 4; j++) {
        int grow = row0 + r4 + j;
        half4v hv;
        if (grow < N_NODES) {
            float di = dinv[grow];
            hv.x = (_Float16)(acc[j].x * di);
            hv.y = (_Float16)(acc[j].y * di);
            hv.z = (_Float16)(acc[j].z * di);
            hv.w = (_Float16)(acc[j].w * di);
        } else {
            hv.x = hv.y = hv.z = hv.w = (_Float16)0.f;  // pad row for dummy edges
        }
        *(half4v*)&hs[grow * HIDDEN + c4] = hv;
    }
}

// ---------------- fused agg1 + relu + layer2: wave per node (12500 blocks) ----------------

__global__ __launch_bounds__(256) void k_agg1_l2(
    const _Float16* __restrict__ hs, const int* __restrict__ row_ptr,
    const int* __restrict__ rec, const float* __restrict__ dinv,
    const float* __restrict__ b1, const float* __restrict__ W2,
    float* __restrict__ zs)
{
    int node = blockIdx.x * 4 + (threadIdx.x >> 6);  // grid 12500, exact
    int lane = threadIdx.x & 63;

    float di = dinv[node];
    float acc = (float)hs[node * HIDDEN + lane];  // self-loop (dinv[node] folded in hs)

    int beg = row_ptr[node];
    int end = row_ptr[node + 1];

    for (int base = beg; base < end; base += 64) {
        int n = end - base;
        if (n > 64) n = 64;
        int r = N_NODES;  // pad: zero row of hs
        if (lane < n) r = rec[base + lane];
        int n4 = (n + 3) & ~3;
        for (int e = 0; e < n4; e += 4) {
            int s0 = __shfl(r, e + 0, 64);
            int s1 = __shfl(r, e + 1, 64);
            int s2 = __shfl(r, e + 2, 64);
            int s3 = __shfl(r, e + 3, 64);
            float v0 = (float)hs[s0 * HIDDEN + lane];
            float v1 = (float)hs[s1 * HIDDEN + lane];
            float v2 = (float)hs[s2 * HIDDEN + lane];
            float v3 = (float)hs[s3 * HIDDEN + lane];
            acc += v0 + v1;
            acc += v2 + v3;
        }
    }
    acc *= di;

    float y = fmaxf(acc + b1[lane], 0.0f);
    float p0 = y * W2[lane * N_CLASSES + 0];
    float p1 = y * W2[lane * N_CLASSES + 1];
#pragma unroll
    for (int off = 32; off > 0; off >>= 1) {
        p0 += __shfl_down(p0, off, 64);
        p1 += __shfl_down(p1, off, 64);
    }
    if (lane == 0) {
        zs[node * 2 + 0] = p0 * di;  // pre-scaled for layer-2 aggregation
        zs[node * 2 + 1] = p1 * di;
    }
}

// ---------------- agg2: wave per node; out = b2 + di*(sum_nbr zs[src] + zs[node]) ----------------

__global__ __launch_bounds__(256) void k_agg2(
    const float* __restrict__ zs, const int* __restrict__ row_ptr,
    const int* __restrict__ rec, const float* __restrict__ dinv,
    const float* __restrict__ b2, float* __restrict__ out)
{
    int node = blockIdx.x * 4 + (threadIdx.x >> 6);  // grid 12500, exact
    int lane = threadIdx.x & 63;
    int beg = row_ptr[node];
    int end = row_ptr[node + 1];
    float a0 = 0.f, a1 = 0.f;
    for (int idx = beg + lane; idx < end; idx += 64) {
        int s = rec[idx];
        float2 v = *(const float2*)&zs[s * 2];
        a0 += v.x;
        a1 += v.y;
    }
#pragma unroll
    for (int off = 32; off > 0; off >>= 1) {
        a0 += __shfl_down(a0, off, 64);
        a1 += __shfl_down(a1, off, 64);
    }
    if (lane == 0) {
        float di = dinv[node];
        float2 zv = *(const float2*)&zs[node * 2];
        float2 o;
        o.x = fmaf(di, a0 + zv.x, b2[0]);
        o.y = fmaf(di, a1 + zv.y, b2[1]);
        *(float2*)&out[node * 2] = o;
    }
}

// ---------------- launch ----------------

extern "C" void kernel_launch(void* const* d_in, const int* in_sizes, int n_in,
                              void* d_out, int out_size, void* d_ws, size_t ws_size,
                              hipStream_t stream) {
    const float* x  = (const float*)d_in[0];
    const int* ei   = (const int*)d_in[1];
    const float* W1 = (const float*)d_in[2];
    const float* b1 = (const float*)d_in[3];
    const float* W2 = (const float*)d_in[4];
    const float* b2 = (const float*)d_in[5];
    float* out = (float*)d_out;

    const int4* src4 = (const int4*)ei;
    const int4* dst4 = (const int4*)(ei + N_EDGES);

    // workspace layout (4-byte units), ~18.5 MB
    int*      bucket_off = (int*)d_ws;                   // [0, 1024)       783 used
    int*      colsum     = (int*)d_ws + 1024;            // [1024, 2048)
    float*    dinv       = (float*)d_ws + 2048;          // [2048, 52224)
    int*      row_ptr    = (int*)d_ws + 52224;           // 50001 -> pad to 102432
    int*      bhist      = (int*)d_ws + 102432;          // 782*784 -> pad 613120
    int*      excT       = (int*)d_ws + 715552;          // 782*784 -> pad 613120
    int*      ebin       = (int*)d_ws + 1328672;         // 800000 packed ints
    int*      rec        = (int*)d_ws + 2128672;         // 800000 src ints
    _Float16* hs         = (_Float16*)((int*)d_ws + 2928672);  // 50048*64 halves
    float*    zs         = (float*)d_ws + 4530208;       // 100000 floats

    void* args[] = { (void*)&src4, (void*)&dst4, (void*)&bhist, (void*)&excT,
                     (void*)&colsum, (void*)&bucket_off, (void*)&row_ptr,
                     (void*)&dinv, (void*)&ebin, (void*)&rec };
    hipLaunchCooperativeKernel(reinterpret_cast<void*>(k_csr_build),
                               dim3(NBLK), dim3(256), args, 0, stream);

    k_gemm1<<<(N_NODES + 63) / 64, 256, 0, stream>>>(x, W1, dinv, hs);
    k_agg1_l2<<<N_NODES / 4, 256, 0, stream>>>(hs, row_ptr, rec, dinv, b1, W2, zs);
    k_agg2<<<N_NODES / 4, 256, 0, stream>>>(zs, row_ptr, rec, dinv, b2, out);
}

// Round 10
// 158.309 us; speedup vs baseline: 3.2000x; 3.2000x over previous
//
#include <hip/hip_runtime.h>

#define N_NODES 50000
#define N_EDGES 800000
#define D_IN 128
#define HIDDEN 64
#define N_CLASSES 2
#define NBUK 782        // ceil(50000/64) buckets of 64 nodes
#define NBUK_P 784      // padded stride (bhist rows)
#define NBLK 782        // edge-chunk blocks: 782*256 threads * 4 edges >= 800000
#define NBLK_P 784      // padded stride (excT rows)

typedef _Float16 half4v __attribute__((ext_vector_type(4)));

// ---------------- phase 1: per-chunk LDS histogram over dst buckets ----------------

__global__ __launch_bounds__(256) void k_hist(const int4* __restrict__ dst4,
                                              int* __restrict__ bhist) {
    __shared__ int hist[NBUK];
    int t = threadIdx.x;
    for (int i = t; i < NBUK; i += 256) hist[i] = 0;
    __syncthreads();
    int idx = blockIdx.x * 256 + t;
    if (idx < N_EDGES / 4) {
        int4 d = dst4[idx];
        atomicAdd(&hist[d.x >> 6], 1);
        atomicAdd(&hist[d.y >> 6], 1);
        atomicAdd(&hist[d.z >> 6], 1);
        atomicAdd(&hist[d.w >> 6], 1);
    }
    __syncthreads();
    for (int i = t; i < NBUK; i += 256) bhist[blockIdx.x * NBUK_P + i] = hist[i];
}

// ---------------- phase 2: column scan over chunks; excT transposed ----------------

__global__ __launch_bounds__(256) void k_colscan(const int* __restrict__ bhist,
                                                 int* __restrict__ excT,
                                                 int* __restrict__ colsum) {
    __shared__ int part[256];
    int b = blockIdx.x;   // bucket
    int t = threadIdx.x;
    int v[4];
    int s = 0;
#pragma unroll
    for (int i = 0; i < 4; i++) {
        int blk = t * 4 + i;
        v[i] = (blk < NBLK) ? bhist[blk * NBUK_P + b] : 0;
        s += v[i];
    }
    part[t] = s;
    __syncthreads();
    for (int off = 1; off < 256; off <<= 1) {
        int p = (t >= off) ? part[t - off] : 0;
        __syncthreads();
        part[t] += p;
        __syncthreads();
    }
    int run = (t == 0) ? 0 : part[t - 1];
#pragma unroll
    for (int i = 0; i < 4; i++) {
        int blk = t * 4 + i;
        if (blk < NBLK) excT[b * NBLK_P + blk] = run;
        run += v[i];
    }
    if (t == 255) colsum[b] = run;
}

// ---------------- phase 3: scatter with inline bucket-offset scan ----------------
// Every block redundantly scans the 782 colsums (L2-hot, ~2us) -> no separate
// dispatch and no grid.sync (R9 lesson: grid.sync costs ~75us on 782 blocks).
// Block 0 publishes bucket_off for k_bucket_csr. pk = (src << 7) | (dst & 63).

__global__ __launch_bounds__(256) void k_binA2s(const int4* __restrict__ src4,
                                                const int4* __restrict__ dst4,
                                                const int* __restrict__ excT,
                                                const int* __restrict__ colsum,
                                                int* __restrict__ bucket_off,
                                                int* __restrict__ row_ptr,
                                                int* __restrict__ ebin) {
    __shared__ int part[256];
    __shared__ int cur[NBUK];
    const int b = blockIdx.x;
    const int t = threadIdx.x;

    int v[4];
    int s = 0;
#pragma unroll
    for (int i = 0; i < 4; i++) {
        int idx = t * 4 + i;
        v[i] = (idx < NBUK) ? colsum[idx] : 0;
        s += v[i];
    }
    part[t] = s;
    __syncthreads();
    for (int off = 1; off < 256; off <<= 1) {
        int p = (t >= off) ? part[t - off] : 0;
        __syncthreads();
        part[t] += p;
        __syncthreads();
    }
    int run = (t == 0) ? 0 : part[t - 1];
#pragma unroll
    for (int i = 0; i < 4; i++) {
        int idx = t * 4 + i;
        if (idx < NBUK) {
            cur[idx] = run + excT[idx * NBLK_P + b];
            if (b == 0) bucket_off[idx] = run;
            run += v[i];
        } else if (idx == NBUK && b == 0) {
            bucket_off[idx] = run;  // == N_EDGES
        }
    }
    if (b == 0 && t == 0) row_ptr[N_NODES] = N_EDGES;
    __syncthreads();

    int idx = b * 256 + t;
    if (idx < N_EDGES / 4) {
        int4 sv = src4[idx];
        int4 d = dst4[idx];
        int p0 = atomicAdd(&cur[d.x >> 6], 1);
        int p1 = atomicAdd(&cur[d.y >> 6], 1);
        int p2 = atomicAdd(&cur[d.z >> 6], 1);
        int p3 = atomicAdd(&cur[d.w >> 6], 1);
        ebin[p0] = (sv.x << 7) | (d.x & 63);
        ebin[p1] = (sv.y << 7) | (d.y & 63);
        ebin[p2] = (sv.z << 7) | (d.z & 63);
        ebin[p3] = (sv.w << 7) | (d.w & 63);
    }
}

// ---------------- phase 4: per-bucket CSR: degree count + scan + node-sorted scatter ----------------

__global__ __launch_bounds__(256) void k_bucket_csr(const int* __restrict__ ebin,
                                                    const int* __restrict__ bucket_off,
                                                    int* __restrict__ row_ptr,
                                                    float* __restrict__ dinv,
                                                    int* __restrict__ rec) {
    __shared__ int cnt[64];
    __shared__ int cur[64];
    int b = blockIdx.x;
    int t = threadIdx.x;
    if (t < 64) cnt[t] = 0;
    __syncthreads();
    int beg = bucket_off[b], end = bucket_off[b + 1];
    for (int i = beg + t; i < end; i += 256) atomicAdd(&cnt[ebin[i] & 63], 1);
    __syncthreads();
    if (t < 64) {
        int deg = cnt[t];
        int sum = deg;  // inclusive wave scan over 64 lanes
#pragma unroll
        for (int off = 1; off < 64; off <<= 1) {
            int v = __shfl_up(sum, off, 64);
            if (t >= off) sum += v;
        }
        int rp = beg + sum - deg;
        cur[t] = rp;
        int node = b * 64 + t;
        if (node < N_NODES) {
            row_ptr[node] = rp;
            dinv[node] = rsqrtf((float)(deg + 1));  // +1 self-loop
        }
    }
    __syncthreads();
    for (int i = beg + t; i < end; i += 256) {
        int pk = ebin[i];
        int pos = atomicAdd(&cur[pk & 63], 1);
        rec[pos] = pk >> 7;
    }
}

// ---------------- GEMM1: hs = (x @ W1) * dinv[row], fp16; pad rows zeroed ----------------

__device__ inline void fma4(float4& acc, float s, const float4& w) {
    acc.x = fmaf(s, w.x, acc.x);
    acc.y = fmaf(s, w.y, acc.y);
    acc.z = fmaf(s, w.z, acc.z);
    acc.w = fmaf(s, w.w, acc.w);
}

__global__ __launch_bounds__(256) void k_gemm1(
    const float* __restrict__ x, const float* __restrict__ W1,
    const float* __restrict__ dinv, _Float16* __restrict__ hs)
{
    __shared__ float Ws[D_IN * HIDDEN];  // 32KB
    __shared__ float xs[64 * D_IN];      // 32KB
    const int tid = threadIdx.x;
    const int row0 = blockIdx.x * 64;

    const float4* W4 = (const float4*)W1;
    float4* Ws4 = (float4*)Ws;
    for (int i = tid; i < D_IN * HIDDEN / 4; i += 256) Ws4[i] = W4[i];

    for (int i = tid; i < 64 * D_IN / 4; i += 256) {
        int r = i >> 5;
        int k4 = (i & 31) << 2;
        float4 v = make_float4(0.f, 0.f, 0.f, 0.f);
        int grow = row0 + r;
        if (grow < N_NODES) v = *(const float4*)&x[grow * D_IN + k4];
        int sw = ((r >> 2) & 1) << 4;
        *(float4*)&xs[r * D_IN + (k4 ^ sw)] = v;
    }
    __syncthreads();

    const int c4 = (tid & 15) * 4;
    const int r4 = (tid >> 4) * 4;
    float4 acc[4];
#pragma unroll
    for (int j = 0; j < 4; j++) acc[j] = make_float4(0.f, 0.f, 0.f, 0.f);

    for (int k = 0; k < D_IN; k += 4) {
        float4 w0 = *(const float4*)&Ws[(k + 0) * HIDDEN + c4];
        float4 w1 = *(const float4*)&Ws[(k + 1) * HIDDEN + c4];
        float4 w2 = *(const float4*)&Ws[(k + 2) * HIDDEN + c4];
        float4 w3 = *(const float4*)&Ws[(k + 3) * HIDDEN + c4];
        float4 a[4];
#pragma unroll
        for (int j = 0; j < 4; j++) {
            int r = r4 + j;
            int sw = ((r >> 2) & 1) << 4;
            a[j] = *(const float4*)&xs[r * D_IN + (k ^ sw)];
        }
#pragma unroll
        for (int j = 0; j < 4; j++) {
            fma4(acc[j], a[j].x, w0);
            fma4(acc[j], a[j].y, w1);
            fma4(acc[j], a[j].z, w2);
            fma4(acc[j], a[j].w, w3);
        }
    }

#pragma unroll
    for (int j = 0; j < 4; j++) {
        int grow = row0 + r4 + j;
        half4v hv;
        if (grow < N_NODES) {
            float di = dinv[grow];
            hv.x = (_Float16)(acc[j].x * di);
            hv.y = (_Float16)(acc[j].y * di);
            hv.z = (_Float16)(acc[j].z * di);
            hv.w = (_Float16)(acc[j].w * di);
        } else {
            hv.x = hv.y = hv.z = hv.w = (_Float16)0.f;  // pad row for dummy edges
        }
        *(half4v*)&hs[grow * HIDDEN + c4] = hv;
    }
}

// ---------------- fused agg1 + relu + layer2: wave per node, 4 edges per load ----------------
// lane = (edge-slot q = lane>>4, feature-quad f = lane&15). Each 8B half4v load
// fetches 4 features; the 4 slots process 4 edges concurrently -> per 16 edges:
// 4 bpermutes + 4 loads (vs 16+16 in the 1-feat/lane version). Cross-slot
// combine via shfl_xor(16), shfl_xor(32).

__global__ __launch_bounds__(256) void k_agg1_l2(
    const _Float16* __restrict__ hs, const int* __restrict__ row_ptr,
    const int* __restrict__ rec, const float* __restrict__ dinv,
    const float* __restrict__ b1, const float* __restrict__ W2,
    float* __restrict__ zs)
{
    const int node = blockIdx.x * 4 + (threadIdx.x >> 6);  // grid 12500, exact
    const int lane = threadIdx.x & 63;
    const int q = lane >> 4;   // edge slot 0..3
    const int f = lane & 15;   // feature quad 0..15
    const half4v* H = (const half4v*)hs;

    float di = dinv[node];
    float4 acc = make_float4(0.f, 0.f, 0.f, 0.f);

    int beg = row_ptr[node];
    int end = row_ptr[node + 1];

    for (int base = beg; base < end; base += 64) {
        int n = end - base;
        if (n > 64) n = 64;
        int r = N_NODES;  // pad: zero row of hs
        if (lane < n) r = rec[base + lane];
        int n16 = (n + 15) & ~15;
        for (int e = 0; e < n16; e += 16) {
            int s0 = __shfl(r, e + q, 64);
            int s1 = __shfl(r, e + 4 + q, 64);
            int s2 = __shfl(r, e + 8 + q, 64);
            int s3 = __shfl(r, e + 12 + q, 64);
            half4v a0 = H[s0 * 16 + f];
            half4v a1 = H[s1 * 16 + f];
            half4v a2 = H[s2 * 16 + f];
            half4v a3 = H[s3 * 16 + f];
            acc.x += (float)a0.x + (float)a1.x + (float)a2.x + (float)a3.x;
            acc.y += (float)a0.y + (float)a1.y + (float)a2.y + (float)a3.y;
            acc.z += (float)a0.z + (float)a1.z + (float)a2.z + (float)a3.z;
            acc.w += (float)a0.w + (float)a1.w + (float)a2.w + (float)a3.w;
        }
    }

    // combine the 4 edge slots (butterfly over lane bits 4,5)
    acc.x += __shfl_xor(acc.x, 16, 64);
    acc.y += __shfl_xor(acc.y, 16, 64);
    acc.z += __shfl_xor(acc.z, 16, 64);
    acc.w += __shfl_xor(acc.w, 16, 64);
    acc.x += __shfl_xor(acc.x, 32, 64);
    acc.y += __shfl_xor(acc.y, 32, 64);
    acc.z += __shfl_xor(acc.z, 32, 64);
    acc.w += __shfl_xor(acc.w, 32, 64);

    // self-loop (identical on all lanes with same f -> stays consistent)
    half4v sv = H[node * 16 + f];
    acc.x += (float)sv.x;
    acc.y += (float)sv.y;
    acc.z += (float)sv.z;
    acc.w += (float)sv.w;

    // y = relu(di*acc + b1); p = y @ W2 (per-lane 4-feature partial dot)
    float4 bb = ((const float4*)b1)[f];
    float4 y;
    y.x = fmaxf(fmaf(acc.x, di, bb.x), 0.f);
    y.y = fmaxf(fmaf(acc.y, di, bb.y), 0.f);
    y.z = fmaxf(fmaf(acc.z, di, bb.z), 0.f);
    y.w = fmaxf(fmaf(acc.w, di, bb.w), 0.f);
    float4 wA = ((const float4*)W2)[2 * f];      // rows 4f, 4f+1
    float4 wB = ((const float4*)W2)[2 * f + 1];  // rows 4f+2, 4f+3
    float p0 = y.x * wA.x + y.y * wA.z + y.z * wB.x + y.w * wB.z;
    float p1 = y.x * wA.y + y.y * wA.w + y.z * wB.y + y.w * wB.w;

    // reduce over the 16 feature-quads (lanes 16+ hold duplicates; only lane 0's result used)
    p0 += __shfl_down(p0, 8, 64);
    p1 += __shfl_down(p1, 8, 64);
    p0 += __shfl_down(p0, 4, 64);
    p1 += __shfl_down(p1, 4, 64);
    p0 += __shfl_down(p0, 2, 64);
    p1 += __shfl_down(p1, 2, 64);
    p0 += __shfl_down(p0, 1, 64);
    p1 += __shfl_down(p1, 1, 64);
    if (lane == 0) {
        zs[node * 2 + 0] = p0 * di;  // pre-scaled for layer-2 aggregation
        zs[node * 2 + 1] = p1 * di;
    }
}

// ---------------- agg2: wave per node; out = b2 + di*(sum_nbr zs[src] + zs[node]) ----------------

__global__ __launch_bounds__(256) void k_agg2(
    const float* __restrict__ zs, const int* __restrict__ row_ptr,
    const int* __restrict__ rec, const float* __restrict__ dinv,
    const float* __restrict__ b2, float* __restrict__ out)
{
    int node = blockIdx.x * 4 + (threadIdx.x >> 6);  // grid 12500, exact
    int lane = threadIdx.x & 63;
    int beg = row_ptr[node];
    int end = row_ptr[node + 1];
    float a0 = 0.f, a1 = 0.f;
    for (int idx = beg + lane; idx < end; idx += 64) {
        int s = rec[idx];
        float2 v = *(const float2*)&zs[s * 2];
        a0 += v.x;
        a1 += v.y;
    }
#pragma unroll
    for (int off = 32; off > 0; off >>= 1) {
        a0 += __shfl_down(a0, off, 64);
        a1 += __shfl_down(a1, off, 64);
    }
    if (lane == 0) {
        float di = dinv[node];
        float2 zv = *(const float2*)&zs[node * 2];
        float2 o;
        o.x = fmaf(di, a0 + zv.x, b2[0]);
        o.y = fmaf(di, a1 + zv.y, b2[1]);
        *(float2*)&out[node * 2] = o;
    }
}

// ---------------- launch ----------------

extern "C" void kernel_launch(void* const* d_in, const int* in_sizes, int n_in,
                              void* d_out, int out_size, void* d_ws, size_t ws_size,
                              hipStream_t stream) {
    const float* x  = (const float*)d_in[0];
    const int* ei   = (const int*)d_in[1];
    const float* W1 = (const float*)d_in[2];
    const float* b1 = (const float*)d_in[3];
    const float* W2 = (const float*)d_in[4];
    const float* b2 = (const float*)d_in[5];
    float* out = (float*)d_out;

    const int4* src4 = (const int4*)ei;
    const int4* dst4 = (const int4*)(ei + N_EDGES);

    // workspace layout (4-byte units), ~18.5 MB
    int*      bucket_off = (int*)d_ws;                   // [0, 1024)       783 used
    int*      colsum     = (int*)d_ws + 1024;            // [1024, 2048)
    float*    dinv       = (float*)d_ws + 2048;          // [2048, 52224)
    int*      row_ptr    = (int*)d_ws + 52224;           // 50001 -> pad to 102432
    int*      bhist      = (int*)d_ws + 102432;          // 782*784 -> pad 613120
    int*      excT       = (int*)d_ws + 715552;          // 782*784 -> pad 613120
    int*      ebin       = (int*)d_ws + 1328672;         // 800000 packed ints
    int*      rec        = (int*)d_ws + 2128672;         // 800000 src ints
    _Float16* hs         = (_Float16*)((int*)d_ws + 2928672);  // 50048*64 halves
    float*    zs         = (float*)d_ws + 4530208;       // 100000 floats

    k_hist<<<NBLK, 256, 0, stream>>>(dst4, bhist);
    k_colscan<<<NBUK, 256, 0, stream>>>(bhist, excT, colsum);
    k_binA2s<<<NBLK, 256, 0, stream>>>(src4, dst4, excT, colsum, bucket_off, row_ptr, ebin);
    k_bucket_csr<<<NBUK, 256, 0, stream>>>(ebin, bucket_off, row_ptr, dinv, rec);
    k_gemm1<<<(N_NODES + 63) / 64, 256, 0, stream>>>(x, W1, dinv, hs);
    k_agg1_l2<<<N_NODES / 4, 256, 0, stream>>>(hs, row_ptr, rec, dinv, b1, W2, zs);
    k_agg2<<<N_NODES / 4, 256, 0, stream>>>(zs, row_ptr, rec, dinv, b2, out);
}

// Round 11
// 146.054 us; speedup vs baseline: 3.4685x; 1.0839x over previous
//
#include <hip/hip_runtime.h>

#define N_NODES 50000
#define N_EDGES 800000
#define D_IN 128
#define HIDDEN 64
#define N_CLASSES 2
#define NBUK 782        // ceil(50000/64) buckets of 64 nodes
#define NBUK_P 784      // padded stride (bhist rows)
#define NBLK 782        // edge-chunk blocks: 782*256 threads * 4 edges >= 800000
#define NBLK_P 784      // padded stride (excT rows)
#define XPAD 136        // fp16 LDS row stride (128 + 8 pad: 16B-aligned, ~2-way banks)

typedef _Float16 half4v __attribute__((ext_vector_type(4)));
typedef _Float16 h8 __attribute__((ext_vector_type(8)));
typedef float f4 __attribute__((ext_vector_type(4)));

// ---------------- phase 1: per-chunk LDS histogram over dst buckets ----------------

__global__ __launch_bounds__(256) void k_hist(const int4* __restrict__ dst4,
                                              int* __restrict__ bhist) {
    __shared__ int hist[NBUK];
    int t = threadIdx.x;
    for (int i = t; i < NBUK; i += 256) hist[i] = 0;
    __syncthreads();
    int idx = blockIdx.x * 256 + t;
    if (idx < N_EDGES / 4) {
        int4 d = dst4[idx];
        atomicAdd(&hist[d.x >> 6], 1);
        atomicAdd(&hist[d.y >> 6], 1);
        atomicAdd(&hist[d.z >> 6], 1);
        atomicAdd(&hist[d.w >> 6], 1);
    }
    __syncthreads();
    for (int i = t; i < NBUK; i += 256) bhist[blockIdx.x * NBUK_P + i] = hist[i];
}

// ---------------- phase 2: column scan over chunks; excT transposed ----------------

__global__ __launch_bounds__(256) void k_colscan(const int* __restrict__ bhist,
                                                 int* __restrict__ excT,
                                                 int* __restrict__ colsum) {
    __shared__ int part[256];
    int b = blockIdx.x;   // bucket
    int t = threadIdx.x;
    int v[4];
    int s = 0;
#pragma unroll
    for (int i = 0; i < 4; i++) {
        int blk = t * 4 + i;
        v[i] = (blk < NBLK) ? bhist[blk * NBUK_P + b] : 0;
        s += v[i];
    }
    part[t] = s;
    __syncthreads();
    for (int off = 1; off < 256; off <<= 1) {
        int p = (t >= off) ? part[t - off] : 0;
        __syncthreads();
        part[t] += p;
        __syncthreads();
    }
    int run = (t == 0) ? 0 : part[t - 1];
#pragma unroll
    for (int i = 0; i < 4; i++) {
        int blk = t * 4 + i;
        if (blk < NBLK) excT[b * NBLK_P + blk] = run;
        run += v[i];
    }
    if (t == 255) colsum[b] = run;
}

// ---------------- phase 3: scatter with inline bucket-offset scan ----------------
// Every block redundantly scans the 782 colsums (L2-hot) -> no separate dispatch,
// no grid.sync (R9: grid.sync costs ~75us on 782 blocks). pk = (src<<7)|(dst&63).

__global__ __launch_bounds__(256) void k_binA2s(const int4* __restrict__ src4,
                                                const int4* __restrict__ dst4,
                                                const int* __restrict__ excT,
                                                const int* __restrict__ colsum,
                                                int* __restrict__ bucket_off,
                                                int* __restrict__ row_ptr,
                                                int* __restrict__ ebin) {
    __shared__ int part[256];
    __shared__ int cur[NBUK];
    const int b = blockIdx.x;
    const int t = threadIdx.x;

    int v[4];
    int s = 0;
#pragma unroll
    for (int i = 0; i < 4; i++) {
        int idx = t * 4 + i;
        v[i] = (idx < NBUK) ? colsum[idx] : 0;
        s += v[i];
    }
    part[t] = s;
    __syncthreads();
    for (int off = 1; off < 256; off <<= 1) {
        int p = (t >= off) ? part[t - off] : 0;
        __syncthreads();
        part[t] += p;
        __syncthreads();
    }
    int run = (t == 0) ? 0 : part[t - 1];
#pragma unroll
    for (int i = 0; i < 4; i++) {
        int idx = t * 4 + i;
        if (idx < NBUK) {
            cur[idx] = run + excT[idx * NBLK_P + b];
            if (b == 0) bucket_off[idx] = run;
            run += v[i];
        } else if (idx == NBUK && b == 0) {
            bucket_off[idx] = run;  // == N_EDGES
        }
    }
    if (b == 0 && t == 0) row_ptr[N_NODES] = N_EDGES;
    __syncthreads();

    int idx = b * 256 + t;
    if (idx < N_EDGES / 4) {
        int4 sv = src4[idx];
        int4 d = dst4[idx];
        int p0 = atomicAdd(&cur[d.x >> 6], 1);
        int p1 = atomicAdd(&cur[d.y >> 6], 1);
        int p2 = atomicAdd(&cur[d.z >> 6], 1);
        int p3 = atomicAdd(&cur[d.w >> 6], 1);
        ebin[p0] = (sv.x << 7) | (d.x & 63);
        ebin[p1] = (sv.y << 7) | (d.y & 63);
        ebin[p2] = (sv.z << 7) | (d.z & 63);
        ebin[p3] = (sv.w << 7) | (d.w & 63);
    }
}

// ---------------- phase 4 (merged): per-bucket CSR + MFMA fp16 GEMM tile ----------------
// Block b owns nodes [b*64, b*64+64): builds their CSR rows (count/scan/scatter),
// keeps dinv in LDS, then computes hs = (x@W1)*dinv for the same 64 rows via
// v_mfma_f32_16x16x32_f16 (fp32 accumulate). Layouts (verified, cdna docs):
//   A-frag:  m = lane&15, k = (lane>>4)*8 + j   (8 halves, b128 from LDS)
//   B-frag:  n = lane&15, k = (lane>>4)*8 + j   (W1 stored transposed Wt[n][k])
//   C/D:     n = lane&15, m = (lane>>4)*4 + reg

__global__ __launch_bounds__(256) void k_csr_gemm(
    const int* __restrict__ ebin, const int* __restrict__ bucket_off,
    const float* __restrict__ x, const float* __restrict__ W1,
    int* __restrict__ row_ptr, float* __restrict__ dinv_g,
    int* __restrict__ rec, _Float16* __restrict__ hs)
{
    __shared__ _Float16 xs[64 * XPAD];   // 17.0 KB
    __shared__ _Float16 Wt[64 * XPAD];   // 17.0 KB  (Wt[n][k])
    __shared__ int cnt[64];
    __shared__ int cur[64];
    __shared__ float sdinv[64];
    const int b = blockIdx.x;
    const int t = threadIdx.x;
    const int row0 = b * 64;

    // --- stage x tile fp32->fp16 (coalesced float4 reads, b64 LDS writes) ---
    for (int i4 = t; i4 < 64 * D_IN / 4; i4 += 256) {
        int r = i4 >> 5;
        int k4 = (i4 & 31) << 2;
        int grow = row0 + r;
        half4v hv;
        if (grow < N_NODES) {
            float4 v = *(const float4*)&x[grow * D_IN + k4];
            hv.x = (_Float16)v.x; hv.y = (_Float16)v.y;
            hv.z = (_Float16)v.z; hv.w = (_Float16)v.w;
        } else {
            hv.x = hv.y = hv.z = hv.w = (_Float16)0.f;  // pad rows stay zero
        }
        *(half4v*)&xs[r * XPAD + k4] = hv;
    }
    // --- stage W1 transposed fp32->fp16 (8K elements, scalar LDS writes ok) ---
    for (int i4 = t; i4 < D_IN * HIDDEN / 4; i4 += 256) {
        float4 v = *(const float4*)&W1[i4 * 4];
        int k = i4 >> 4;
        int n = (i4 & 15) << 2;
        Wt[(n + 0) * XPAD + k] = (_Float16)v.x;
        Wt[(n + 1) * XPAD + k] = (_Float16)v.y;
        Wt[(n + 2) * XPAD + k] = (_Float16)v.z;
        Wt[(n + 3) * XPAD + k] = (_Float16)v.w;
    }

    // --- CSR phase: degree count + wave scan + node-sorted scatter ---
    if (t < 64) cnt[t] = 0;
    __syncthreads();
    int beg = bucket_off[b], end = bucket_off[b + 1];
    for (int i = beg + t; i < end; i += 256) atomicAdd(&cnt[ebin[i] & 63], 1);
    __syncthreads();
    if (t < 64) {
        int deg = cnt[t];
        int sum = deg;  // inclusive wave scan over 64 lanes
#pragma unroll
        for (int off = 1; off < 64; off <<= 1) {
            int v = __shfl_up(sum, off, 64);
            if (t >= off) sum += v;
        }
        int rp = beg + sum - deg;
        cur[t] = rp;
        float di = rsqrtf((float)(deg + 1));  // +1 self-loop
        sdinv[t] = di;
        int node = row0 + t;
        if (node < N_NODES) {
            row_ptr[node] = rp;
            dinv_g[node] = di;
        }
    }
    __syncthreads();
    for (int i = beg + t; i < end; i += 256) {
        int pk = ebin[i];
        int pos = atomicAdd(&cur[pk & 63], 1);
        rec[pos] = pk >> 7;
    }
    __syncthreads();  // staging + CSR complete

    // --- MFMA: wave w owns rows [w*16, w*16+16); 4 n-tiles; K=128 in 4 steps ---
    const int w = t >> 6;
    const int L = t & 63;
    const int mrow = w * 16 + (L & 15);
    const int qk = (L >> 4) * 8;
    f4 acc0 = {0.f, 0.f, 0.f, 0.f}, acc1 = acc0, acc2 = acc0, acc3 = acc0;
#pragma unroll
    for (int ks = 0; ks < D_IN; ks += 32) {
        h8 a = *(const h8*)&xs[mrow * XPAD + ks + qk];
        h8 b0 = *(const h8*)&Wt[(0 * 16 + (L & 15)) * XPAD + ks + qk];
        h8 b1 = *(const h8*)&Wt[(1 * 16 + (L & 15)) * XPAD + ks + qk];
        h8 b2 = *(const h8*)&Wt[(2 * 16 + (L & 15)) * XPAD + ks + qk];
        h8 b3 = *(const h8*)&Wt[(3 * 16 + (L & 15)) * XPAD + ks + qk];
        acc0 = __builtin_amdgcn_mfma_f32_16x16x32_f16(a, b0, acc0, 0, 0, 0);
        acc1 = __builtin_amdgcn_mfma_f32_16x16x32_f16(a, b1, acc1, 0, 0, 0);
        acc2 = __builtin_amdgcn_mfma_f32_16x16x32_f16(a, b2, acc2, 0, 0, 0);
        acc3 = __builtin_amdgcn_mfma_f32_16x16x32_f16(a, b3, acc3, 0, 0, 0);
    }

    // --- epilogue: hs[node][col] = acc * dinv (pad rows: acc==0 -> stays 0) ---
    const int n0 = L & 15;
#pragma unroll
    for (int j = 0; j < 4; j++) {
        int m = w * 16 + (L >> 4) * 4 + j;
        float di = sdinv[m];
        size_t base = (size_t)(row0 + m) * HIDDEN;
        hs[base + 0 * 16 + n0] = (_Float16)(acc0[j] * di);
        hs[base + 1 * 16 + n0] = (_Float16)(acc1[j] * di);
        hs[base + 2 * 16 + n0] = (_Float16)(acc2[j] * di);
        hs[base + 3 * 16 + n0] = (_Float16)(acc3[j] * di);
    }
}

// ---------------- fused agg1 + relu + layer2: wave per node, 4 edges per load ----------------
// lane = (edge-slot q = lane>>4, feature-quad f = lane&15); 8B half4v gathers.

__global__ __launch_bounds__(256) void k_agg1_l2(
    const _Float16* __restrict__ hs, const int* __restrict__ row_ptr,
    const int* __restrict__ rec, const float* __restrict__ dinv,
    const float* __restrict__ b1, const float* __restrict__ W2,
    float* __restrict__ zs)
{
    const int node = blockIdx.x * 4 + (threadIdx.x >> 6);  // grid 12500, exact
    const int lane = threadIdx.x & 63;
    const int q = lane >> 4;   // edge slot 0..3
    const int f = lane & 15;   // feature quad 0..15
    const half4v* H = (const half4v*)hs;

    float di = dinv[node];
    float4 acc = make_float4(0.f, 0.f, 0.f, 0.f);

    int beg = row_ptr[node];
    int end = row_ptr[node + 1];

    for (int base = beg; base < end; base += 64) {
        int n = end - base;
        if (n > 64) n = 64;
        int r = N_NODES;  // pad: zero row of hs
        if (lane < n) r = rec[base + lane];
        int n16 = (n + 15) & ~15;
        for (int e = 0; e < n16; e += 16) {
            int s0 = __shfl(r, e + q, 64);
            int s1 = __shfl(r, e + 4 + q, 64);
            int s2 = __shfl(r, e + 8 + q, 64);
            int s3 = __shfl(r, e + 12 + q, 64);
            half4v a0 = H[s0 * 16 + f];
            half4v a1 = H[s1 * 16 + f];
            half4v a2 = H[s2 * 16 + f];
            half4v a3 = H[s3 * 16 + f];
            acc.x += (float)a0.x + (float)a1.x + (float)a2.x + (float)a3.x;
            acc.y += (float)a0.y + (float)a1.y + (float)a2.y + (float)a3.y;
            acc.z += (float)a0.z + (float)a1.z + (float)a2.z + (float)a3.z;
            acc.w += (float)a0.w + (float)a1.w + (float)a2.w + (float)a3.w;
        }
    }

    // combine the 4 edge slots (butterfly over lane bits 4,5)
    acc.x += __shfl_xor(acc.x, 16, 64);
    acc.y += __shfl_xor(acc.y, 16, 64);
    acc.z += __shfl_xor(acc.z, 16, 64);
    acc.w += __shfl_xor(acc.w, 16, 64);
    acc.x += __shfl_xor(acc.x, 32, 64);
    acc.y += __shfl_xor(acc.y, 32, 64);
    acc.z += __shfl_xor(acc.z, 32, 64);
    acc.w += __shfl_xor(acc.w, 32, 64);

    // self-loop
    half4v sv = H[node * 16 + f];
    acc.x += (float)sv.x;
    acc.y += (float)sv.y;
    acc.z += (float)sv.z;
    acc.w += (float)sv.w;

    // y = relu(di*acc + b1); p = y @ W2 (per-lane 4-feature partial dot)
    float4 bb = ((const float4*)b1)[f];
    float4 y;
    y.x = fmaxf(fmaf(acc.x, di, bb.x), 0.f);
    y.y = fmaxf(fmaf(acc.y, di, bb.y), 0.f);
    y.z = fmaxf(fmaf(acc.z, di, bb.z), 0.f);
    y.w = fmaxf(fmaf(acc.w, di, bb.w), 0.f);
    float4 wA = ((const float4*)W2)[2 * f];      // rows 4f, 4f+1
    float4 wB = ((const float4*)W2)[2 * f + 1];  // rows 4f+2, 4f+3
    float p0 = y.x * wA.x + y.y * wA.z + y.z * wB.x + y.w * wB.z;
    float p1 = y.x * wA.y + y.y * wA.w + y.z * wB.y + y.w * wB.w;

    p0 += __shfl_down(p0, 8, 64);
    p1 += __shfl_down(p1, 8, 64);
    p0 += __shfl_down(p0, 4, 64);
    p1 += __shfl_down(p1, 4, 64);
    p0 += __shfl_down(p0, 2, 64);
    p1 += __shfl_down(p1, 2, 64);
    p0 += __shfl_down(p0, 1, 64);
    p1 += __shfl_down(p1, 1, 64);
    if (lane == 0) {
        zs[node * 2 + 0] = p0 * di;  // pre-scaled for layer-2 aggregation
        zs[node * 2 + 1] = p1 * di;
    }
}

// ---------------- agg2: wave per node; out = b2 + di*(sum_nbr zs[src] + zs[node]) ----------------

__global__ __launch_bounds__(256) void k_agg2(
    const float* __restrict__ zs, const int* __restrict__ row_ptr,
    const int* __restrict__ rec, const float* __restrict__ dinv,
    const float* __restrict__ b2, float* __restrict__ out)
{
    int node = blockIdx.x * 4 + (threadIdx.x >> 6);  // grid 12500, exact
    int lane = threadIdx.x & 63;
    int beg = row_ptr[node];
    int end = row_ptr[node + 1];
    float a0 = 0.f, a1 = 0.f;
    for (int idx = beg + lane; idx < end; idx += 64) {
        int s = rec[idx];
        float2 v = *(const float2*)&zs[s * 2];
        a0 += v.x;
        a1 += v.y;
    }
#pragma unroll
    for (int off = 32; off > 0; off >>= 1) {
        a0 += __shfl_down(a0, off, 64);
        a1 += __shfl_down(a1, off, 64);
    }
    if (lane == 0) {
        float di = dinv[node];
        float2 zv = *(const float2*)&zs[node * 2];
        float2 o;
        o.x = fmaf(di, a0 + zv.x, b2[0]);
        o.y = fmaf(di, a1 + zv.y, b2[1]);
        *(float2*)&out[node * 2] = o;
    }
}

// ---------------- launch ----------------

extern "C" void kernel_launch(void* const* d_in, const int* in_sizes, int n_in,
                              void* d_out, int out_size, void* d_ws, size_t ws_size,
                              hipStream_t stream) {
    const float* x  = (const float*)d_in[0];
    const int* ei   = (const int*)d_in[1];
    const float* W1 = (const float*)d_in[2];
    const float* b1 = (const float*)d_in[3];
    const float* W2 = (const float*)d_in[4];
    const float* b2 = (const float*)d_in[5];
    float* out = (float*)d_out;

    const int4* src4 = (const int4*)ei;
    const int4* dst4 = (const int4*)(ei + N_EDGES);

    // workspace layout (4-byte units), ~18.5 MB
    int*      bucket_off = (int*)d_ws;                   // [0, 1024)       783 used
    int*      colsum     = (int*)d_ws + 1024;            // [1024, 2048)
    float*    dinv       = (float*)d_ws + 2048;          // [2048, 52224)
    int*      row_ptr    = (int*)d_ws + 52224;           // 50001 -> pad to 102432
    int*      bhist      = (int*)d_ws + 102432;          // 782*784 -> pad 613120
    int*      excT       = (int*)d_ws + 715552;          // 782*784 -> pad 613120
    int*      ebin       = (int*)d_ws + 1328672;         // 800000 packed ints
    int*      rec        = (int*)d_ws + 2128672;         // 800000 src ints
    _Float16* hs         = (_Float16*)((int*)d_ws + 2928672);  // 50048*64 halves
    float*    zs         = (float*)d_ws + 4530208;       // 100000 floats

    k_hist<<<NBLK, 256, 0, stream>>>(dst4, bhist);
    k_colscan<<<NBUK, 256, 0, stream>>>(bhist, excT, colsum);
    k_binA2s<<<NBLK, 256, 0, stream>>>(src4, dst4, excT, colsum, bucket_off, row_ptr, ebin);
    k_csr_gemm<<<NBUK, 256, 0, stream>>>(ebin, bucket_off, x, W1, row_ptr, dinv, rec, hs);
    k_agg1_l2<<<N_NODES / 4, 256, 0, stream>>>(hs, row_ptr, rec, dinv, b1, W2, zs);
    k_agg2<<<N_NODES / 4, 256, 0, stream>>>(zs, row_ptr, rec, dinv, b2, out);
}

// Round 12
// 139.713 us; speedup vs baseline: 3.6259x; 1.0454x over previous
//
#include <hip/hip_runtime.h>

#define N_NODES 50000
#define N_EDGES 800000
#define D_IN 128
#define HIDDEN 64
#define N_CLASSES 2
#define NBUK 782        // ceil(50000/64) buckets of 64 nodes
#define NBUK_P 784      // padded stride (bhist rows)
#define NBLK 196        // edge-chunk blocks: 196*4096 >= 800000
#define NBLK_P 200      // padded stride (excT rows)
#define NE4 200000      // N_EDGES/4
#define XPAD 136        // fp16 LDS row stride (128 + 8 pad)

typedef _Float16 half4v __attribute__((ext_vector_type(4)));
typedef _Float16 h8 __attribute__((ext_vector_type(8)));
typedef float f4 __attribute__((ext_vector_type(4)));

// ---------------- phase 1: per-chunk LDS histogram over dst buckets ----------------
// 196 blocks x 4096 edges (16/thread): chunk-matrix traffic 4x smaller than 782-chunk version.

__global__ __launch_bounds__(256) void k_hist(const int4* __restrict__ dst4,
                                              int* __restrict__ bhist) {
    __shared__ int hist[NBUK];
    int t = threadIdx.x;
    for (int i = t; i < NBUK; i += 256) hist[i] = 0;
    __syncthreads();
    int base4 = blockIdx.x * 1024;
#pragma unroll
    for (int k = 0; k < 4; k++) {
        int idx = base4 + k * 256 + t;
        if (idx < NE4) {
            int4 d = dst4[idx];
            atomicAdd(&hist[d.x >> 6], 1);
            atomicAdd(&hist[d.y >> 6], 1);
            atomicAdd(&hist[d.z >> 6], 1);
            atomicAdd(&hist[d.w >> 6], 1);
        }
    }
    __syncthreads();
    for (int i = t; i < NBUK; i += 256) bhist[blockIdx.x * NBUK_P + i] = hist[i];
}

// ---------------- phase 2: column scan over 196 chunks; excT transposed ----------------

__global__ __launch_bounds__(256) void k_colscan(const int* __restrict__ bhist,
                                                 int* __restrict__ excT,
                                                 int* __restrict__ colsum) {
    __shared__ int part[256];
    int b = blockIdx.x;   // bucket
    int t = threadIdx.x;
    int v = (t < NBLK) ? bhist[t * NBUK_P + b] : 0;
    part[t] = v;
    __syncthreads();
    for (int off = 1; off < 256; off <<= 1) {
        int p = (t >= off) ? part[t - off] : 0;
        __syncthreads();
        part[t] += p;
        __syncthreads();
    }
    if (t < NBLK) excT[b * NBLK_P + t] = part[t] - v;  // exclusive
    if (t == 255) colsum[b] = part[255];
}

// ---------------- phase 3: scatter with inline bucket-offset scan ----------------
// Each of 196 blocks redundantly scans the 782 colsums (L2-hot) -> no separate
// dispatch, no grid.sync (R9: grid.sync ~75us). pk = (src<<7)|(dst&63).

__global__ __launch_bounds__(256) void k_binA2s(const int4* __restrict__ src4,
                                                const int4* __restrict__ dst4,
                                                const int* __restrict__ excT,
                                                const int* __restrict__ colsum,
                                                int* __restrict__ bucket_off,
                                                int* __restrict__ row_ptr,
                                                int* __restrict__ ebin) {
    __shared__ int part[256];
    __shared__ int cur[NBUK];
    const int b = blockIdx.x;
    const int t = threadIdx.x;

    int v[4];
    int s = 0;
#pragma unroll
    for (int i = 0; i < 4; i++) {
        int idx = t * 4 + i;
        v[i] = (idx < NBUK) ? colsum[idx] : 0;
        s += v[i];
    }
    part[t] = s;
    __syncthreads();
    for (int off = 1; off < 256; off <<= 1) {
        int p = (t >= off) ? part[t - off] : 0;
        __syncthreads();
        part[t] += p;
        __syncthreads();
    }
    int run = (t == 0) ? 0 : part[t - 1];
#pragma unroll
    for (int i = 0; i < 4; i++) {
        int idx = t * 4 + i;
        if (idx < NBUK) {
            cur[idx] = run + excT[idx * NBLK_P + b];
            if (b == 0) bucket_off[idx] = run;
            run += v[i];
        } else if (idx == NBUK && b == 0) {
            bucket_off[idx] = run;  // == N_EDGES
        }
    }
    if (b == 0 && t == 0) row_ptr[N_NODES] = N_EDGES;
    __syncthreads();

    int base4 = b * 1024;
#pragma unroll
    for (int k = 0; k < 4; k++) {
        int idx = base4 + k * 256 + t;
        if (idx < NE4) {
            int4 sv = src4[idx];
            int4 d = dst4[idx];
            int p0 = atomicAdd(&cur[d.x >> 6], 1);
            int p1 = atomicAdd(&cur[d.y >> 6], 1);
            int p2 = atomicAdd(&cur[d.z >> 6], 1);
            int p3 = atomicAdd(&cur[d.w >> 6], 1);
            ebin[p0] = (sv.x << 7) | (d.x & 63);
            ebin[p1] = (sv.y << 7) | (d.y & 63);
            ebin[p2] = (sv.z << 7) | (d.z & 63);
            ebin[p3] = (sv.w << 7) | (d.w & 63);
        }
    }
}

// ---------------- phase 4 (merged): per-bucket CSR + MFMA fp16 GEMM tile ----------------
// Block b owns nodes [b*64, b*64+64): builds their CSR rows, keeps dinv in LDS,
// computes hs = (x@W1)*dinv via v_mfma_f32_16x16x32_f16 (fp32 accumulate).
//   A-frag:  m = lane&15, k = (lane>>4)*8 + j
//   B-frag:  n = lane&15, k = (lane>>4)*8 + j   (W1 transposed Wt[n][k])
//   C/D:     n = lane&15, m = (lane>>4)*4 + reg

__global__ __launch_bounds__(256) void k_csr_gemm(
    const int* __restrict__ ebin, const int* __restrict__ bucket_off,
    const float* __restrict__ x, const float* __restrict__ W1,
    int* __restrict__ row_ptr, float* __restrict__ dinv_g,
    int* __restrict__ rec, _Float16* __restrict__ hs)
{
    __shared__ _Float16 xs[64 * XPAD];   // 17.0 KB
    __shared__ _Float16 Wt[64 * XPAD];   // 17.0 KB  (Wt[n][k])
    __shared__ int cnt[64];
    __shared__ int cur[64];
    __shared__ float sdinv[64];
    const int b = blockIdx.x;
    const int t = threadIdx.x;
    const int row0 = b * 64;

    // --- stage x tile fp32->fp16 ---
    for (int i4 = t; i4 < 64 * D_IN / 4; i4 += 256) {
        int r = i4 >> 5;
        int k4 = (i4 & 31) << 2;
        int grow = row0 + r;
        half4v hv;
        if (grow < N_NODES) {
            float4 v = *(const float4*)&x[grow * D_IN + k4];
            hv.x = (_Float16)v.x; hv.y = (_Float16)v.y;
            hv.z = (_Float16)v.z; hv.w = (_Float16)v.w;
        } else {
            hv.x = hv.y = hv.z = hv.w = (_Float16)0.f;  // pad rows stay zero
        }
        *(half4v*)&xs[r * XPAD + k4] = hv;
    }
    // --- stage W1 transposed fp32->fp16 ---
    for (int i4 = t; i4 < D_IN * HIDDEN / 4; i4 += 256) {
        float4 v = *(const float4*)&W1[i4 * 4];
        int k = i4 >> 4;
        int n = (i4 & 15) << 2;
        Wt[(n + 0) * XPAD + k] = (_Float16)v.x;
        Wt[(n + 1) * XPAD + k] = (_Float16)v.y;
        Wt[(n + 2) * XPAD + k] = (_Float16)v.z;
        Wt[(n + 3) * XPAD + k] = (_Float16)v.w;
    }

    // --- CSR phase: degree count + wave scan + node-sorted scatter ---
    if (t < 64) cnt[t] = 0;
    __syncthreads();
    int beg = bucket_off[b], end = bucket_off[b + 1];
    for (int i = beg + t; i < end; i += 256) atomicAdd(&cnt[ebin[i] & 63], 1);
    __syncthreads();
    if (t < 64) {
        int deg = cnt[t];
        int sum = deg;  // inclusive wave scan over 64 lanes
#pragma unroll
        for (int off = 1; off < 64; off <<= 1) {
            int v = __shfl_up(sum, off, 64);
            if (t >= off) sum += v;
        }
        int rp = beg + sum - deg;
        cur[t] = rp;
        float di = rsqrtf((float)(deg + 1));  // +1 self-loop
        sdinv[t] = di;
        int node = row0 + t;
        if (node < N_NODES) {
            row_ptr[node] = rp;
            dinv_g[node] = di;
        }
    }
    __syncthreads();
    for (int i = beg + t; i < end; i += 256) {
        int pk = ebin[i];
        int pos = atomicAdd(&cur[pk & 63], 1);
        rec[pos] = pk >> 7;
    }
    __syncthreads();  // staging + CSR complete

    // --- MFMA: wave w owns rows [w*16, w*16+16); 4 n-tiles; K=128 in 4 steps ---
    const int w = t >> 6;
    const int L = t & 63;
    const int mrow = w * 16 + (L & 15);
    const int qk = (L >> 4) * 8;
    f4 acc0 = {0.f, 0.f, 0.f, 0.f}, acc1 = acc0, acc2 = acc0, acc3 = acc0;
#pragma unroll
    for (int ks = 0; ks < D_IN; ks += 32) {
        h8 a = *(const h8*)&xs[mrow * XPAD + ks + qk];
        h8 b0 = *(const h8*)&Wt[(0 * 16 + (L & 15)) * XPAD + ks + qk];
        h8 b1 = *(const h8*)&Wt[(1 * 16 + (L & 15)) * XPAD + ks + qk];
        h8 b2 = *(const h8*)&Wt[(2 * 16 + (L & 15)) * XPAD + ks + qk];
        h8 b3 = *(const h8*)&Wt[(3 * 16 + (L & 15)) * XPAD + ks + qk];
        acc0 = __builtin_amdgcn_mfma_f32_16x16x32_f16(a, b0, acc0, 0, 0, 0);
        acc1 = __builtin_amdgcn_mfma_f32_16x16x32_f16(a, b1, acc1, 0, 0, 0);
        acc2 = __builtin_amdgcn_mfma_f32_16x16x32_f16(a, b2, acc2, 0, 0, 0);
        acc3 = __builtin_amdgcn_mfma_f32_16x16x32_f16(a, b3, acc3, 0, 0, 0);
    }

    // --- epilogue: hs[node][col] = acc * dinv ---
    const int n0 = L & 15;
#pragma unroll
    for (int j = 0; j < 4; j++) {
        int m = w * 16 + (L >> 4) * 4 + j;
        float di = sdinv[m];
        size_t base = (size_t)(row0 + m) * HIDDEN;
        hs[base + 0 * 16 + n0] = (_Float16)(acc0[j] * di);
        hs[base + 1 * 16 + n0] = (_Float16)(acc1[j] * di);
        hs[base + 2 * 16 + n0] = (_Float16)(acc2[j] * di);
        hs[base + 3 * 16 + n0] = (_Float16)(acc3[j] * di);
    }
}

// ---------------- fused agg1 + relu + layer2: wave per node, 4 edges per load ----------------
// lane = (edge-slot q = lane>>4, feature-quad f = lane&15); 8B half4v gathers.

__global__ __launch_bounds__(256) void k_agg1_l2(
    const _Float16* __restrict__ hs, const int* __restrict__ row_ptr,
    const int* __restrict__ rec, const float* __restrict__ dinv,
    const float* __restrict__ b1, const float* __restrict__ W2,
    float* __restrict__ zs)
{
    const int node = blockIdx.x * 4 + (threadIdx.x >> 6);  // grid 12500, exact
    const int lane = threadIdx.x & 63;
    const int q = lane >> 4;   // edge slot 0..3
    const int f = lane & 15;   // feature quad 0..15
    const half4v* H = (const half4v*)hs;

    float di = dinv[node];
    float4 acc = make_float4(0.f, 0.f, 0.f, 0.f);

    int beg = row_ptr[node];
    int end = row_ptr[node + 1];

    for (int base = beg; base < end; base += 64) {
        int n = end - base;
        if (n > 64) n = 64;
        int r = N_NODES;  // pad: zero row of hs
        if (lane < n) r = rec[base + lane];
        int n16 = (n + 15) & ~15;
        for (int e = 0; e < n16; e += 16) {
            int s0 = __shfl(r, e + q, 64);
            int s1 = __shfl(r, e + 4 + q, 64);
            int s2 = __shfl(r, e + 8 + q, 64);
            int s3 = __shfl(r, e + 12 + q, 64);
            half4v a0 = H[s0 * 16 + f];
            half4v a1 = H[s1 * 16 + f];
            half4v a2 = H[s2 * 16 + f];
            half4v a3 = H[s3 * 16 + f];
            acc.x += (float)a0.x + (float)a1.x + (float)a2.x + (float)a3.x;
            acc.y += (float)a0.y + (float)a1.y + (float)a2.y + (float)a3.y;
            acc.z += (float)a0.z + (float)a1.z + (float)a2.z + (float)a3.z;
            acc.w += (float)a0.w + (float)a1.w + (float)a2.w + (float)a3.w;
        }
    }

    // combine the 4 edge slots (butterfly over lane bits 4,5)
    acc.x += __shfl_xor(acc.x, 16, 64);
    acc.y += __shfl_xor(acc.y, 16, 64);
    acc.z += __shfl_xor(acc.z, 16, 64);
    acc.w += __shfl_xor(acc.w, 16, 64);
    acc.x += __shfl_xor(acc.x, 32, 64);
    acc.y += __shfl_xor(acc.y, 32, 64);
    acc.z += __shfl_xor(acc.z, 32, 64);
    acc.w += __shfl_xor(acc.w, 32, 64);

    // self-loop
    half4v sv = H[node * 16 + f];
    acc.x += (float)sv.x;
    acc.y += (float)sv.y;
    acc.z += (float)sv.z;
    acc.w += (float)sv.w;

    // y = relu(di*acc + b1); p = y @ W2 (per-lane 4-feature partial dot)
    float4 bb = ((const float4*)b1)[f];
    float4 y;
    y.x = fmaxf(fmaf(acc.x, di, bb.x), 0.f);
    y.y = fmaxf(fmaf(acc.y, di, bb.y), 0.f);
    y.z = fmaxf(fmaf(acc.z, di, bb.z), 0.f);
    y.w = fmaxf(fmaf(acc.w, di, bb.w), 0.f);
    float4 wA = ((const float4*)W2)[2 * f];      // rows 4f, 4f+1
    float4 wB = ((const float4*)W2)[2 * f + 1];  // rows 4f+2, 4f+3
    float p0 = y.x * wA.x + y.y * wA.z + y.z * wB.x + y.w * wB.z;
    float p1 = y.x * wA.y + y.y * wA.w + y.z * wB.y + y.w * wB.w;

    p0 += __shfl_down(p0, 8, 64);
    p1 += __shfl_down(p1, 8, 64);
    p0 += __shfl_down(p0, 4, 64);
    p1 += __shfl_down(p1, 4, 64);
    p0 += __shfl_down(p0, 2, 64);
    p1 += __shfl_down(p1, 2, 64);
    p0 += __shfl_down(p0, 1, 64);
    p1 += __shfl_down(p1, 1, 64);
    if (lane == 0) {
        zs[node * 2 + 0] = p0 * di;  // pre-scaled for layer-2 aggregation
        zs[node * 2 + 1] = p1 * di;
    }
}

// ---------------- agg2: wave per node; out = b2 + di*(sum_nbr zs[src] + zs[node]) ----------------

__global__ __launch_bounds__(256) void k_agg2(
    const float* __restrict__ zs, const int* __restrict__ row_ptr,
    const int* __restrict__ rec, const float* __restrict__ dinv,
    const float* __restrict__ b2, float* __restrict__ out)
{
    int node = blockIdx.x * 4 + (threadIdx.x >> 6);  // grid 12500, exact
    int lane = threadIdx.x & 63;
    int beg = row_ptr[node];
    int end = row_ptr[node + 1];
    float a0 = 0.f, a1 = 0.f;
    for (int idx = beg + lane; idx < end; idx += 64) {
        int s = rec[idx];
        float2 v = *(const float2*)&zs[s * 2];
        a0 += v.x;
        a1 += v.y;
    }
#pragma unroll
    for (int off = 32; off > 0; off >>= 1) {
        a0 += __shfl_down(a0, off, 64);
        a1 += __shfl_down(a1, off, 64);
    }
    if (lane == 0) {
        float di = dinv[node];
        float2 zv = *(const float2*)&zs[node * 2];
        float2 o;
        o.x = fmaf(di, a0 + zv.x, b2[0]);
        o.y = fmaf(di, a1 + zv.y, b2[1]);
        *(float2*)&out[node * 2] = o;
    }
}

// ---------------- launch ----------------

extern "C" void kernel_launch(void* const* d_in, const int* in_sizes, int n_in,
                              void* d_out, int out_size, void* d_ws, size_t ws_size,
                              hipStream_t stream) {
    const float* x  = (const float*)d_in[0];
    const int* ei   = (const int*)d_in[1];
    const float* W1 = (const float*)d_in[2];
    const float* b1 = (const float*)d_in[3];
    const float* W2 = (const float*)d_in[4];
    const float* b2 = (const float*)d_in[5];
    float* out = (float*)d_out;

    const int4* src4 = (const int4*)ei;
    const int4* dst4 = (const int4*)(ei + N_EDGES);

    // workspace layout (4-byte units), ~14 MB
    int*      bucket_off = (int*)d_ws;                   // [0, 1024)       783 used
    int*      colsum     = (int*)d_ws + 1024;            // [1024, 2048)
    float*    dinv       = (float*)d_ws + 2048;          // [2048, 52224)
    int*      row_ptr    = (int*)d_ws + 52224;           // 50001 -> pad to 102432
    int*      bhist      = (int*)d_ws + 102432;          // 196*784 = 153664 -> pad 153696
    int*      excT       = (int*)d_ws + 256128;          // 782*200 = 156400 -> pad 156448
    int*      ebin       = (int*)d_ws + 412576;          // 800000 packed ints
    int*      rec        = (int*)d_ws + 1212576;         // 800000 src ints
    _Float16* hs         = (_Float16*)((int*)d_ws + 2012576);  // 50048*64 halves
    float*    zs         = (float*)d_ws + 3614112;       // 100000 floats

    k_hist<<<NBLK, 256, 0, stream>>>(dst4, bhist);
    k_colscan<<<NBUK, 256, 0, stream>>>(bhist, excT, colsum);
    k_binA2s<<<NBLK, 256, 0, stream>>>(src4, dst4, excT, colsum, bucket_off, row_ptr, ebin);
    k_csr_gemm<<<NBUK, 256, 0, stream>>>(ebin, bucket_off, x, W1, row_ptr, dinv, rec, hs);
    k_agg1_l2<<<N_NODES / 4, 256, 0, stream>>>(hs, row_ptr, rec, dinv, b1, W2, zs);
    k_agg2<<<N_NODES / 4, 256, 0, stream>>>(zs, row_ptr, rec, dinv, b2, out);
}

// Round 13
// 131.960 us; speedup vs baseline: 3.8390x; 1.0588x over previous
//
#include <hip/hip_runtime.h>

#define N_NODES 50000
#define N_EDGES 800000
#define D_IN 128
#define HIDDEN 64
#define N_CLASSES 2
#define NBUK 782        // ceil(50000/64) buckets of 64 nodes
#define NBUK_P 784      // padded stride (bhist rows)
#define NBLK 196        // edge-chunk blocks: 196*4096 >= 800000
#define NBLK_P 200      // padded stride (excT rows)
#define NE4 200000      // N_EDGES/4
#define XPAD 136        // fp16 LDS row stride (128 + 8 pad)

typedef _Float16 half4v __attribute__((ext_vector_type(4)));
typedef _Float16 h8 __attribute__((ext_vector_type(8)));
typedef float f4 __attribute__((ext_vector_type(4)));

// ---------------- phase 1: per-chunk LDS histogram over dst buckets ----------------

__global__ __launch_bounds__(256) void k_hist(const int4* __restrict__ dst4,
                                              int* __restrict__ bhist) {
    __shared__ int hist[NBUK];
    int t = threadIdx.x;
    for (int i = t; i < NBUK; i += 256) hist[i] = 0;
    __syncthreads();
    int base4 = blockIdx.x * 1024;
#pragma unroll
    for (int k = 0; k < 4; k++) {
        int idx = base4 + k * 256 + t;
        if (idx < NE4) {
            int4 d = dst4[idx];
            atomicAdd(&hist[d.x >> 6], 1);
            atomicAdd(&hist[d.y >> 6], 1);
            atomicAdd(&hist[d.z >> 6], 1);
            atomicAdd(&hist[d.w >> 6], 1);
        }
    }
    __syncthreads();
    for (int i = t; i < NBUK; i += 256) bhist[blockIdx.x * NBUK_P + i] = hist[i];
}

// ---------------- phase 2: column scan over 196 chunks; excT transposed ----------------

__global__ __launch_bounds__(256) void k_colscan(const int* __restrict__ bhist,
                                                 int* __restrict__ excT,
                                                 int* __restrict__ colsum) {
    __shared__ int part[256];
    int b = blockIdx.x;   // bucket
    int t = threadIdx.x;
    int v = (t < NBLK) ? bhist[t * NBUK_P + b] : 0;
    part[t] = v;
    __syncthreads();
    for (int off = 1; off < 256; off <<= 1) {
        int p = (t >= off) ? part[t - off] : 0;
        __syncthreads();
        part[t] += p;
        __syncthreads();
    }
    if (t < NBLK) excT[b * NBLK_P + t] = part[t] - v;  // exclusive
    if (t == 255) colsum[b] = part[255];
}

// ---------------- phase 3: scatter with inline bucket-offset scan ----------------
// Each of 196 blocks redundantly scans the 782 colsums (L2-hot) -> no separate
// dispatch, no grid.sync (R9: grid.sync ~75us). pk = (src<<7)|(dst&63).

__global__ __launch_bounds__(256) void k_binA2s(const int4* __restrict__ src4,
                                                const int4* __restrict__ dst4,
                                                const int* __restrict__ excT,
                                                const int* __restrict__ colsum,
                                                int* __restrict__ bucket_off,
                                                int* __restrict__ row_ptr,
                                                int* __restrict__ ebin) {
    __shared__ int part[256];
    __shared__ int cur[NBUK];
    const int b = blockIdx.x;
    const int t = threadIdx.x;

    int v[4];
    int s = 0;
#pragma unroll
    for (int i = 0; i < 4; i++) {
        int idx = t * 4 + i;
        v[i] = (idx < NBUK) ? colsum[idx] : 0;
        s += v[i];
    }
    part[t] = s;
    __syncthreads();
    for (int off = 1; off < 256; off <<= 1) {
        int p = (t >= off) ? part[t - off] : 0;
        __syncthreads();
        part[t] += p;
        __syncthreads();
    }
    int run = (t == 0) ? 0 : part[t - 1];
#pragma unroll
    for (int i = 0; i < 4; i++) {
        int idx = t * 4 + i;
        if (idx < NBUK) {
            cur[idx] = run + excT[idx * NBLK_P + b];
            if (b == 0) bucket_off[idx] = run;
            run += v[i];
        } else if (idx == NBUK && b == 0) {
            bucket_off[idx] = run;  // == N_EDGES
        }
    }
    if (b == 0 && t == 0) row_ptr[N_NODES] = N_EDGES;
    __syncthreads();

    int base4 = b * 1024;
#pragma unroll
    for (int k = 0; k < 4; k++) {
        int idx = base4 + k * 256 + t;
        if (idx < NE4) {
            int4 sv = src4[idx];
            int4 d = dst4[idx];
            int p0 = atomicAdd(&cur[d.x >> 6], 1);
            int p1 = atomicAdd(&cur[d.y >> 6], 1);
            int p2 = atomicAdd(&cur[d.z >> 6], 1);
            int p3 = atomicAdd(&cur[d.w >> 6], 1);
            ebin[p0] = (sv.x << 7) | (d.x & 63);
            ebin[p1] = (sv.y << 7) | (d.y & 63);
            ebin[p2] = (sv.z << 7) | (d.z & 63);
            ebin[p3] = (sv.w << 7) | (d.w & 63);
        }
    }
}

// ---------------- phase 4 (merged): per-bucket CSR + MFMA fp16 GEMM tile ----------------
// Block b owns nodes [b*64, b*64+64): builds their CSR rows, keeps dinv in LDS,
// computes hs = (x@W1)*dinv via v_mfma_f32_16x16x32_f16 (fp32 accumulate).
//   A-frag:  m = lane&15, k = (lane>>4)*8 + j
//   B-frag:  n = lane&15, k = (lane>>4)*8 + j   (W1 transposed Wt[n][k])
//   C/D:     n = lane&15, m = (lane>>4)*4 + reg

__global__ __launch_bounds__(256) void k_csr_gemm(
    const int* __restrict__ ebin, const int* __restrict__ bucket_off,
    const float* __restrict__ x, const float* __restrict__ W1,
    int* __restrict__ row_ptr, float* __restrict__ dinv_g,
    int* __restrict__ rec, _Float16* __restrict__ hs)
{
    __shared__ _Float16 xs[64 * XPAD];   // 17.0 KB
    __shared__ _Float16 Wt[64 * XPAD];   // 17.0 KB  (Wt[n][k])
    __shared__ int cnt[64];
    __shared__ int cur[64];
    __shared__ float sdinv[64];
    const int b = blockIdx.x;
    const int t = threadIdx.x;
    const int row0 = b * 64;

    // --- stage x tile fp32->fp16 ---
    for (int i4 = t; i4 < 64 * D_IN / 4; i4 += 256) {
        int r = i4 >> 5;
        int k4 = (i4 & 31) << 2;
        int grow = row0 + r;
        half4v hv;
        if (grow < N_NODES) {
            float4 v = *(const float4*)&x[grow * D_IN + k4];
            hv.x = (_Float16)v.x; hv.y = (_Float16)v.y;
            hv.z = (_Float16)v.z; hv.w = (_Float16)v.w;
        } else {
            hv.x = hv.y = hv.z = hv.w = (_Float16)0.f;  // pad rows stay zero
        }
        *(half4v*)&xs[r * XPAD + k4] = hv;
    }
    // --- stage W1 transposed fp32->fp16 ---
    for (int i4 = t; i4 < D_IN * HIDDEN / 4; i4 += 256) {
        float4 v = *(const float4*)&W1[i4 * 4];
        int k = i4 >> 4;
        int n = (i4 & 15) << 2;
        Wt[(n + 0) * XPAD + k] = (_Float16)v.x;
        Wt[(n + 1) * XPAD + k] = (_Float16)v.y;
        Wt[(n + 2) * XPAD + k] = (_Float16)v.z;
        Wt[(n + 3) * XPAD + k] = (_Float16)v.w;
    }

    // --- CSR phase: degree count + wave scan + node-sorted scatter ---
    if (t < 64) cnt[t] = 0;
    __syncthreads();
    int beg = bucket_off[b], end = bucket_off[b + 1];
    for (int i = beg + t; i < end; i += 256) atomicAdd(&cnt[ebin[i] & 63], 1);
    __syncthreads();
    if (t < 64) {
        int deg = cnt[t];
        int sum = deg;  // inclusive wave scan over 64 lanes
#pragma unroll
        for (int off = 1; off < 64; off <<= 1) {
            int v = __shfl_up(sum, off, 64);
            if (t >= off) sum += v;
        }
        int rp = beg + sum - deg;
        cur[t] = rp;
        float di = rsqrtf((float)(deg + 1));  // +1 self-loop
        sdinv[t] = di;
        int node = row0 + t;
        if (node < N_NODES) {
            row_ptr[node] = rp;
            dinv_g[node] = di;
        }
    }
    __syncthreads();
    for (int i = beg + t; i < end; i += 256) {
        int pk = ebin[i];
        int pos = atomicAdd(&cur[pk & 63], 1);
        rec[pos] = pk >> 7;
    }
    __syncthreads();  // staging + CSR complete

    // --- MFMA: wave w owns rows [w*16, w*16+16); 4 n-tiles; K=128 in 4 steps ---
    const int w = t >> 6;
    const int L = t & 63;
    const int mrow = w * 16 + (L & 15);
    const int qk = (L >> 4) * 8;
    f4 acc0 = {0.f, 0.f, 0.f, 0.f}, acc1 = acc0, acc2 = acc0, acc3 = acc0;
#pragma unroll
    for (int ks = 0; ks < D_IN; ks += 32) {
        h8 a = *(const h8*)&xs[mrow * XPAD + ks + qk];
        h8 b0 = *(const h8*)&Wt[(0 * 16 + (L & 15)) * XPAD + ks + qk];
        h8 b1 = *(const h8*)&Wt[(1 * 16 + (L & 15)) * XPAD + ks + qk];
        h8 b2 = *(const h8*)&Wt[(2 * 16 + (L & 15)) * XPAD + ks + qk];
        h8 b3 = *(const h8*)&Wt[(3 * 16 + (L & 15)) * XPAD + ks + qk];
        acc0 = __builtin_amdgcn_mfma_f32_16x16x32_f16(a, b0, acc0, 0, 0, 0);
        acc1 = __builtin_amdgcn_mfma_f32_16x16x32_f16(a, b1, acc1, 0, 0, 0);
        acc2 = __builtin_amdgcn_mfma_f32_16x16x32_f16(a, b2, acc2, 0, 0, 0);
        acc3 = __builtin_amdgcn_mfma_f32_16x16x32_f16(a, b3, acc3, 0, 0, 0);
    }

    // --- epilogue: hs[node][col] = acc * dinv ---
    const int n0 = L & 15;
#pragma unroll
    for (int j = 0; j < 4; j++) {
        int m = w * 16 + (L >> 4) * 4 + j;
        float di = sdinv[m];
        size_t base = (size_t)(row0 + m) * HIDDEN;
        hs[base + 0 * 16 + n0] = (_Float16)(acc0[j] * di);
        hs[base + 1 * 16 + n0] = (_Float16)(acc1[j] * di);
        hs[base + 2 * 16 + n0] = (_Float16)(acc2[j] * di);
        hs[base + 3 * 16 + n0] = (_Float16)(acc3[j] * di);
    }
}

// ---------------- fused agg1 + relu + layer2: 2 nodes per wave, 8 gathers in flight ----------------
// Half-wave (32 lanes) per node: q = edge-slot (2), f = feature-quad (16).
// Per 16-edge group: 8 independent 512B gather insts (4 rows each) -> 2x MLP
// vs the 1-node/wave version, half the waves, same bytes.

__global__ __launch_bounds__(256) void k_agg1_l2(
    const _Float16* __restrict__ hs, const int* __restrict__ row_ptr,
    const int* __restrict__ rec, const float* __restrict__ dinv,
    const float* __restrict__ b1, const float* __restrict__ W2,
    float* __restrict__ zs)
{
    const int node = blockIdx.x * 8 + (threadIdx.x >> 5);  // grid 6250, exact
    const int hl = threadIdx.x & 31;   // lane within half-wave
    const int q = hl >> 4;             // edge slot 0..1
    const int f = hl & 15;             // feature quad 0..15
    const int hbase = threadIdx.x & 32;  // shfl base of this half within the wave
    const half4v* H = (const half4v*)hs;

    float di = dinv[node];
    float4 acc = make_float4(0.f, 0.f, 0.f, 0.f);

    int beg = row_ptr[node];
    int end = row_ptr[node + 1];

    for (int base = beg; base < end; base += 32) {
        int n = end - base;
        if (n > 32) n = 32;
        int r = N_NODES;  // pad: zero row of hs
        if (hl < n) r = rec[base + hl];
        int n16 = (n + 15) & ~15;
        for (int e = 0; e < n16; e += 16) {
            int i0 = hbase + e + q;  // this slot's first edge within the half
            int s0 = __shfl(r, i0 + 0, 64);
            int s1 = __shfl(r, i0 + 2, 64);
            int s2 = __shfl(r, i0 + 4, 64);
            int s3 = __shfl(r, i0 + 6, 64);
            int s4 = __shfl(r, i0 + 8, 64);
            int s5 = __shfl(r, i0 + 10, 64);
            int s6 = __shfl(r, i0 + 12, 64);
            int s7 = __shfl(r, i0 + 14, 64);
            half4v a0 = H[s0 * 16 + f];
            half4v a1 = H[s1 * 16 + f];
            half4v a2 = H[s2 * 16 + f];
            half4v a3 = H[s3 * 16 + f];
            half4v a4 = H[s4 * 16 + f];
            half4v a5 = H[s5 * 16 + f];
            half4v a6 = H[s6 * 16 + f];
            half4v a7 = H[s7 * 16 + f];
            acc.x += ((float)a0.x + (float)a1.x) + ((float)a2.x + (float)a3.x)
                   + ((float)a4.x + (float)a5.x) + ((float)a6.x + (float)a7.x);
            acc.y += ((float)a0.y + (float)a1.y) + ((float)a2.y + (float)a3.y)
                   + ((float)a4.y + (float)a5.y) + ((float)a6.y + (float)a7.y);
            acc.z += ((float)a0.z + (float)a1.z) + ((float)a2.z + (float)a3.z)
                   + ((float)a4.z + (float)a5.z) + ((float)a6.z + (float)a7.z);
            acc.w += ((float)a0.w + (float)a1.w) + ((float)a2.w + (float)a3.w)
                   + ((float)a4.w + (float)a5.w) + ((float)a6.w + (float)a7.w);
        }
    }

    // combine the 2 edge slots (within the half-wave)
    acc.x += __shfl_xor(acc.x, 16, 64);
    acc.y += __shfl_xor(acc.y, 16, 64);
    acc.z += __shfl_xor(acc.z, 16, 64);
    acc.w += __shfl_xor(acc.w, 16, 64);

    // self-loop
    half4v sv = H[node * 16 + f];
    acc.x += (float)sv.x;
    acc.y += (float)sv.y;
    acc.z += (float)sv.z;
    acc.w += (float)sv.w;

    // y = relu(di*acc + b1); p = y @ W2 (per-lane 4-feature partial dot)
    float4 bb = ((const float4*)b1)[f];
    float4 y;
    y.x = fmaxf(fmaf(acc.x, di, bb.x), 0.f);
    y.y = fmaxf(fmaf(acc.y, di, bb.y), 0.f);
    y.z = fmaxf(fmaf(acc.z, di, bb.z), 0.f);
    y.w = fmaxf(fmaf(acc.w, di, bb.w), 0.f);
    float4 wA = ((const float4*)W2)[2 * f];      // rows 4f, 4f+1
    float4 wB = ((const float4*)W2)[2 * f + 1];  // rows 4f+2, 4f+3
    float p0 = y.x * wA.x + y.y * wA.z + y.z * wB.x + y.w * wB.z;
    float p1 = y.x * wA.y + y.y * wA.w + y.z * wB.y + y.w * wB.w;

    // reduce over the 16 feature-quads (stays within the half-wave)
    p0 += __shfl_down(p0, 8, 64);
    p1 += __shfl_down(p1, 8, 64);
    p0 += __shfl_down(p0, 4, 64);
    p1 += __shfl_down(p1, 4, 64);
    p0 += __shfl_down(p0, 2, 64);
    p1 += __shfl_down(p1, 2, 64);
    p0 += __shfl_down(p0, 1, 64);
    p1 += __shfl_down(p1, 1, 64);
    if (hl == 0) {
        zs[node * 2 + 0] = p0 * di;  // pre-scaled for layer-2 aggregation
        zs[node * 2 + 1] = p1 * di;
    }
}

// ---------------- agg2: 4 nodes per wave (16 lanes each); all lanes active for deg<=16 ----------------

__global__ __launch_bounds__(256) void k_agg2(
    const float* __restrict__ zs, const int* __restrict__ row_ptr,
    const int* __restrict__ rec, const float* __restrict__ dinv,
    const float* __restrict__ b2, float* __restrict__ out)
{
    const int node = blockIdx.x * 16 + (threadIdx.x >> 4);  // grid 3125, exact
    const int j = threadIdx.x & 15;
    int beg = row_ptr[node];
    int end = row_ptr[node + 1];
    float a0 = 0.f, a1 = 0.f;
    for (int idx = beg + j; idx < end; idx += 16) {
        int s = rec[idx];
        float2 v = *(const float2*)&zs[s * 2];
        a0 += v.x;
        a1 += v.y;
    }
    // reduce within the 16-lane group
    a0 += __shfl_down(a0, 8, 64);
    a1 += __shfl_down(a1, 8, 64);
    a0 += __shfl_down(a0, 4, 64);
    a1 += __shfl_down(a1, 4, 64);
    a0 += __shfl_down(a0, 2, 64);
    a1 += __shfl_down(a1, 2, 64);
    a0 += __shfl_down(a0, 1, 64);
    a1 += __shfl_down(a1, 1, 64);
    if (j == 0) {
        float di = dinv[node];
        float2 zv = *(const float2*)&zs[node * 2];
        float2 o;
        o.x = fmaf(di, a0 + zv.x, b2[0]);
        o.y = fmaf(di, a1 + zv.y, b2[1]);
        *(float2*)&out[node * 2] = o;
    }
}

// ---------------- launch ----------------

extern "C" void kernel_launch(void* const* d_in, const int* in_sizes, int n_in,
                              void* d_out, int out_size, void* d_ws, size_t ws_size,
                              hipStream_t stream) {
    const float* x  = (const float*)d_in[0];
    const int* ei   = (const int*)d_in[1];
    const float* W1 = (const float*)d_in[2];
    const float* b1 = (const float*)d_in[3];
    const float* W2 = (const float*)d_in[4];
    const float* b2 = (const float*)d_in[5];
    float* out = (float*)d_out;

    const int4* src4 = (const int4*)ei;
    const int4* dst4 = (const int4*)(ei + N_EDGES);

    // workspace layout (4-byte units), ~14 MB
    int*      bucket_off = (int*)d_ws;                   // [0, 1024)       783 used
    int*      colsum     = (int*)d_ws + 1024;            // [1024, 2048)
    float*    dinv       = (float*)d_ws + 2048;          // [2048, 52224)
    int*      row_ptr    = (int*)d_ws + 52224;           // 50001 -> pad to 102432
    int*      bhist      = (int*)d_ws + 102432;          // 196*784 = 153664 -> pad 153696
    int*      excT       = (int*)d_ws + 256128;          // 782*200 = 156400 -> pad 156448
    int*      ebin       = (int*)d_ws + 412576;          // 800000 packed ints
    int*      rec        = (int*)d_ws + 1212576;         // 800000 src ints
    _Float16* hs         = (_Float16*)((int*)d_ws + 2012576);  // 50048*64 halves
    float*    zs         = (float*)d_ws + 3614112;       // 100000 floats

    k_hist<<<NBLK, 256, 0, stream>>>(dst4, bhist);
    k_colscan<<<NBUK, 256, 0, stream>>>(bhist, excT, colsum);
    k_binA2s<<<NBLK, 256, 0, stream>>>(src4, dst4, excT, colsum, bucket_off, row_ptr, ebin);
    k_csr_gemm<<<NBUK, 256, 0, stream>>>(ebin, bucket_off, x, W1, row_ptr, dinv, rec, hs);
    k_agg1_l2<<<N_NODES / 8, 256, 0, stream>>>(hs, row_ptr, rec, dinv, b1, W2, zs);
    k_agg2<<<N_NODES / 16, 256, 0, stream>>>(zs, row_ptr, rec, dinv, b2, out);
}

// Round 14
// 128.593 us; speedup vs baseline: 3.9395x; 1.0262x over previous
//
#include <hip/hip_runtime.h>

#define N_NODES 50000
#define N_EDGES 800000
#define D_IN 128
#define HIDDEN 64
#define N_CLASSES 2
#define NBUK 782        // ceil(50000/64) buckets of 64 nodes
#define NBUK_P 784      // padded stride (bhist rows)
#define NBLK 196        // edge-chunk blocks: 196*4096 >= 800000
#define NBLK_P 200      // padded stride (excT rows)
#define NE4 200000      // N_EDGES/4
#define XPAD 136        // fp16 LDS row stride (128 + 8 pad)

typedef _Float16 half4v __attribute__((ext_vector_type(4)));
typedef _Float16 h8 __attribute__((ext_vector_type(8)));
typedef float f4 __attribute__((ext_vector_type(4)));

// ---------------- phase 1: per-chunk LDS histogram over dst buckets ----------------

__global__ __launch_bounds__(256) void k_hist(const int4* __restrict__ dst4,
                                              int* __restrict__ bhist) {
    __shared__ int hist[NBUK];
    int t = threadIdx.x;
    for (int i = t; i < NBUK; i += 256) hist[i] = 0;
    __syncthreads();
    int base4 = blockIdx.x * 1024;
#pragma unroll
    for (int k = 0; k < 4; k++) {
        int idx = base4 + k * 256 + t;
        if (idx < NE4) {
            int4 d = dst4[idx];
            atomicAdd(&hist[d.x >> 6], 1);
            atomicAdd(&hist[d.y >> 6], 1);
            atomicAdd(&hist[d.z >> 6], 1);
            atomicAdd(&hist[d.w >> 6], 1);
        }
    }
    __syncthreads();
    for (int i = t; i < NBUK; i += 256) bhist[blockIdx.x * NBUK_P + i] = hist[i];
}

// ---------------- phase 2: column scan over 196 chunks; excT transposed ----------------

__global__ __launch_bounds__(256) void k_colscan(const int* __restrict__ bhist,
                                                 int* __restrict__ excT,
                                                 int* __restrict__ colsum) {
    __shared__ int part[256];
    int b = blockIdx.x;   // bucket
    int t = threadIdx.x;
    int v = (t < NBLK) ? bhist[t * NBUK_P + b] : 0;
    part[t] = v;
    __syncthreads();
    for (int off = 1; off < 256; off <<= 1) {
        int p = (t >= off) ? part[t - off] : 0;
        __syncthreads();
        part[t] += p;
        __syncthreads();
    }
    if (t < NBLK) excT[b * NBLK_P + t] = part[t] - v;  // exclusive
    if (t == 255) colsum[b] = part[255];
}

// ---------------- phase 3: scatter with inline bucket-offset scan ----------------
// Each of 196 blocks redundantly scans the 782 colsums (L2-hot) -> no separate
// dispatch, no grid.sync (R9: grid.sync ~75us). pk = (src<<7)|(dst&63).

__global__ __launch_bounds__(256) void k_binA2s(const int4* __restrict__ src4,
                                                const int4* __restrict__ dst4,
                                                const int* __restrict__ excT,
                                                const int* __restrict__ colsum,
                                                int* __restrict__ bucket_off,
                                                int* __restrict__ row_ptr,
                                                int* __restrict__ ebin) {
    __shared__ int part[256];
    __shared__ int cur[NBUK];
    const int b = blockIdx.x;
    const int t = threadIdx.x;

    int v[4];
    int s = 0;
#pragma unroll
    for (int i = 0; i < 4; i++) {
        int idx = t * 4 + i;
        v[i] = (idx < NBUK) ? colsum[idx] : 0;
        s += v[i];
    }
    part[t] = s;
    __syncthreads();
    for (int off = 1; off < 256; off <<= 1) {
        int p = (t >= off) ? part[t - off] : 0;
        __syncthreads();
        part[t] += p;
        __syncthreads();
    }
    int run = (t == 0) ? 0 : part[t - 1];
#pragma unroll
    for (int i = 0; i < 4; i++) {
        int idx = t * 4 + i;
        if (idx < NBUK) {
            cur[idx] = run + excT[idx * NBLK_P + b];
            if (b == 0) bucket_off[idx] = run;
            run += v[i];
        } else if (idx == NBUK && b == 0) {
            bucket_off[idx] = run;  // == N_EDGES
        }
    }
    if (b == 0 && t == 0) row_ptr[N_NODES] = N_EDGES;
    __syncthreads();

    int base4 = b * 1024;
#pragma unroll
    for (int k = 0; k < 4; k++) {
        int idx = base4 + k * 256 + t;
        if (idx < NE4) {
            int4 sv = src4[idx];
            int4 d = dst4[idx];
            int p0 = atomicAdd(&cur[d.x >> 6], 1);
            int p1 = atomicAdd(&cur[d.y >> 6], 1);
            int p2 = atomicAdd(&cur[d.z >> 6], 1);
            int p3 = atomicAdd(&cur[d.w >> 6], 1);
            ebin[p0] = (sv.x << 7) | (d.x & 63);
            ebin[p1] = (sv.y << 7) | (d.y & 63);
            ebin[p2] = (sv.z << 7) | (d.z & 63);
            ebin[p3] = (sv.w << 7) | (d.w & 63);
        }
    }
}

// ---------------- phase 4 (merged): per-bucket CSR + MFMA fp16 GEMM tile ----------------
// Block b owns nodes [b*64, b*64+64): builds their CSR rows, keeps dinv in LDS,
// computes hs = (x@W1)*dinv via v_mfma_f32_16x16x32_f16 (fp32 accumulate).
//   A-frag:  m = lane&15, k = (lane>>4)*8 + j
//   B-frag:  n = lane&15, k = (lane>>4)*8 + j   (W1 transposed Wt[n][k])
//   C/D:     n = lane&15, m = (lane>>4)*4 + reg

__global__ __launch_bounds__(256) void k_csr_gemm(
    const int* __restrict__ ebin, const int* __restrict__ bucket_off,
    const float* __restrict__ x, const float* __restrict__ W1,
    int* __restrict__ row_ptr, float* __restrict__ dinv_g,
    int* __restrict__ rec, _Float16* __restrict__ hs)
{
    __shared__ _Float16 xs[64 * XPAD];   // 17.0 KB
    __shared__ _Float16 Wt[64 * XPAD];   // 17.0 KB  (Wt[n][k])
    __shared__ int cnt[64];
    __shared__ int cur[64];
    __shared__ float sdinv[64];
    const int b = blockIdx.x;
    const int t = threadIdx.x;
    const int row0 = b * 64;

    // --- stage x tile fp32->fp16 ---
    for (int i4 = t; i4 < 64 * D_IN / 4; i4 += 256) {
        int r = i4 >> 5;
        int k4 = (i4 & 31) << 2;
        int grow = row0 + r;
        half4v hv;
        if (grow < N_NODES) {
            float4 v = *(const float4*)&x[grow * D_IN + k4];
            hv.x = (_Float16)v.x; hv.y = (_Float16)v.y;
            hv.z = (_Float16)v.z; hv.w = (_Float16)v.w;
        } else {
            hv.x = hv.y = hv.z = hv.w = (_Float16)0.f;  // pad rows stay zero
        }
        *(half4v*)&xs[r * XPAD + k4] = hv;
    }
    // --- stage W1 transposed fp32->fp16 ---
    for (int i4 = t; i4 < D_IN * HIDDEN / 4; i4 += 256) {
        float4 v = *(const float4*)&W1[i4 * 4];
        int k = i4 >> 4;
        int n = (i4 & 15) << 2;
        Wt[(n + 0) * XPAD + k] = (_Float16)v.x;
        Wt[(n + 1) * XPAD + k] = (_Float16)v.y;
        Wt[(n + 2) * XPAD + k] = (_Float16)v.z;
        Wt[(n + 3) * XPAD + k] = (_Float16)v.w;
    }

    // --- CSR phase: degree count + wave scan + node-sorted scatter ---
    if (t < 64) cnt[t] = 0;
    __syncthreads();
    int beg = bucket_off[b], end = bucket_off[b + 1];
    for (int i = beg + t; i < end; i += 256) atomicAdd(&cnt[ebin[i] & 63], 1);
    __syncthreads();
    if (t < 64) {
        int deg = cnt[t];
        int sum = deg;  // inclusive wave scan over 64 lanes
#pragma unroll
        for (int off = 1; off < 64; off <<= 1) {
            int v = __shfl_up(sum, off, 64);
            if (t >= off) sum += v;
        }
        int rp = beg + sum - deg;
        cur[t] = rp;
        float di = rsqrtf((float)(deg + 1));  // +1 self-loop
        sdinv[t] = di;
        int node = row0 + t;
        if (node < N_NODES) {
            row_ptr[node] = rp;
            dinv_g[node] = di;
        }
    }
    __syncthreads();
    for (int i = beg + t; i < end; i += 256) {
        int pk = ebin[i];
        int pos = atomicAdd(&cur[pk & 63], 1);
        rec[pos] = pk >> 7;
    }
    __syncthreads();  // staging + CSR complete

    // --- MFMA: wave w owns rows [w*16, w*16+16); 4 n-tiles; K=128 in 4 steps ---
    const int w = t >> 6;
    const int L = t & 63;
    const int mrow = w * 16 + (L & 15);
    const int qk = (L >> 4) * 8;
    f4 acc0 = {0.f, 0.f, 0.f, 0.f}, acc1 = acc0, acc2 = acc0, acc3 = acc0;
#pragma unroll
    for (int ks = 0; ks < D_IN; ks += 32) {
        h8 a = *(const h8*)&xs[mrow * XPAD + ks + qk];
        h8 b0 = *(const h8*)&Wt[(0 * 16 + (L & 15)) * XPAD + ks + qk];
        h8 b1 = *(const h8*)&Wt[(1 * 16 + (L & 15)) * XPAD + ks + qk];
        h8 b2 = *(const h8*)&Wt[(2 * 16 + (L & 15)) * XPAD + ks + qk];
        h8 b3 = *(const h8*)&Wt[(3 * 16 + (L & 15)) * XPAD + ks + qk];
        acc0 = __builtin_amdgcn_mfma_f32_16x16x32_f16(a, b0, acc0, 0, 0, 0);
        acc1 = __builtin_amdgcn_mfma_f32_16x16x32_f16(a, b1, acc1, 0, 0, 0);
        acc2 = __builtin_amdgcn_mfma_f32_16x16x32_f16(a, b2, acc2, 0, 0, 0);
        acc3 = __builtin_amdgcn_mfma_f32_16x16x32_f16(a, b3, acc3, 0, 0, 0);
    }

    // --- epilogue: hs[node][col] = acc * dinv ---
    const int n0 = L & 15;
#pragma unroll
    for (int j = 0; j < 4; j++) {
        int m = w * 16 + (L >> 4) * 4 + j;
        float di = sdinv[m];
        size_t base = (size_t)(row0 + m) * HIDDEN;
        hs[base + 0 * 16 + n0] = (_Float16)(acc0[j] * di);
        hs[base + 1 * 16 + n0] = (_Float16)(acc1[j] * di);
        hs[base + 2 * 16 + n0] = (_Float16)(acc2[j] * di);
        hs[base + 3 * 16 + n0] = (_Float16)(acc3[j] * di);
    }
}

// ---------------- fused agg1 + relu + layer2: 4 nodes per wave, 32 gathers in flight ----------------
// 16 lanes per node (f = feature-quad). Per 16-edge window: two unrolled groups
// of 8 independent 512B gather insts -> 32 concurrent gathers per wave.
// Reduction chains stay within each 16-lane group (lane0 reads lanes 1/2/4/8).

__global__ __launch_bounds__(256) void k_agg1_l2(
    const _Float16* __restrict__ hs, const int* __restrict__ row_ptr,
    const int* __restrict__ rec, const float* __restrict__ dinv,
    const float* __restrict__ b1, const float* __restrict__ W2,
    float* __restrict__ zs)
{
    const int node = blockIdx.x * 16 + (threadIdx.x >> 4);  // grid 3125, exact
    const int g = threadIdx.x & 15;      // lane in 16-lane group == feature quad
    const int gbase = threadIdx.x & 48;  // group's base lane within the wave
    const half4v* H = (const half4v*)hs;

    float di = dinv[node];
    float4 acc = make_float4(0.f, 0.f, 0.f, 0.f);

    int beg = row_ptr[node];
    int end = row_ptr[node + 1];

    for (int base = beg; base < end; base += 16) {
        int n = end - base;
        if (n > 16) n = 16;
        int r = N_NODES;  // pad: zero row of hs
        if (g < n) r = rec[base + g];
        int n8 = (n + 7) & ~7;
        for (int e = 0; e < n8; e += 8) {
            int i0 = gbase + e;
            int s0 = __shfl(r, i0 + 0, 64);
            int s1 = __shfl(r, i0 + 1, 64);
            int s2 = __shfl(r, i0 + 2, 64);
            int s3 = __shfl(r, i0 + 3, 64);
            int s4 = __shfl(r, i0 + 4, 64);
            int s5 = __shfl(r, i0 + 5, 64);
            int s6 = __shfl(r, i0 + 6, 64);
            int s7 = __shfl(r, i0 + 7, 64);
            half4v a0 = H[s0 * 16 + g];
            half4v a1 = H[s1 * 16 + g];
            half4v a2 = H[s2 * 16 + g];
            half4v a3 = H[s3 * 16 + g];
            half4v a4 = H[s4 * 16 + g];
            half4v a5 = H[s5 * 16 + g];
            half4v a6 = H[s6 * 16 + g];
            half4v a7 = H[s7 * 16 + g];
            acc.x += ((float)a0.x + (float)a1.x) + ((float)a2.x + (float)a3.x)
                   + ((float)a4.x + (float)a5.x) + ((float)a6.x + (float)a7.x);
            acc.y += ((float)a0.y + (float)a1.y) + ((float)a2.y + (float)a3.y)
                   + ((float)a4.y + (float)a5.y) + ((float)a6.y + (float)a7.y);
            acc.z += ((float)a0.z + (float)a1.z) + ((float)a2.z + (float)a3.z)
                   + ((float)a4.z + (float)a5.z) + ((float)a6.z + (float)a7.z);
            acc.w += ((float)a0.w + (float)a1.w) + ((float)a2.w + (float)a3.w)
                   + ((float)a4.w + (float)a5.w) + ((float)a6.w + (float)a7.w);
        }
    }

    // self-loop
    half4v sv = H[node * 16 + g];
    acc.x += (float)sv.x;
    acc.y += (float)sv.y;
    acc.z += (float)sv.z;
    acc.w += (float)sv.w;

    // y = relu(di*acc + b1); p = y @ W2 (per-lane 4-feature partial dot)
    float4 bb = ((const float4*)b1)[g];
    float4 y;
    y.x = fmaxf(fmaf(acc.x, di, bb.x), 0.f);
    y.y = fmaxf(fmaf(acc.y, di, bb.y), 0.f);
    y.z = fmaxf(fmaf(acc.z, di, bb.z), 0.f);
    y.w = fmaxf(fmaf(acc.w, di, bb.w), 0.f);
    float4 wA = ((const float4*)W2)[2 * g];      // rows 4g, 4g+1
    float4 wB = ((const float4*)W2)[2 * g + 1];  // rows 4g+2, 4g+3
    float p0 = y.x * wA.x + y.y * wA.z + y.z * wB.x + y.w * wB.z;
    float p1 = y.x * wA.y + y.y * wA.w + y.z * wB.y + y.w * wB.w;

    // reduce over the 16 feature-quads (lane0's chain uses lanes 1/2/4/8 only)
    p0 += __shfl_down(p0, 8, 64);
    p1 += __shfl_down(p1, 8, 64);
    p0 += __shfl_down(p0, 4, 64);
    p1 += __shfl_down(p1, 4, 64);
    p0 += __shfl_down(p0, 2, 64);
    p1 += __shfl_down(p1, 2, 64);
    p0 += __shfl_down(p0, 1, 64);
    p1 += __shfl_down(p1, 1, 64);
    if (g == 0) {
        zs[node * 2 + 0] = p0 * di;  // pre-scaled for layer-2 aggregation
        zs[node * 2 + 1] = p1 * di;
    }
}

// ---------------- agg2: 8 nodes per wave (8 lanes each) ----------------

__global__ __launch_bounds__(256) void k_agg2(
    const float* __restrict__ zs, const int* __restrict__ row_ptr,
    const int* __restrict__ rec, const float* __restrict__ dinv,
    const float* __restrict__ b2, float* __restrict__ out)
{
    const int node = blockIdx.x * 32 + (threadIdx.x >> 3);  // grid 1563
    const int j = threadIdx.x & 7;
    if (node >= N_NODES) return;
    int beg = row_ptr[node];
    int end = row_ptr[node + 1];
    float a0 = 0.f, a1 = 0.f;
    for (int idx = beg + j; idx < end; idx += 8) {
        int s = rec[idx];
        float2 v = *(const float2*)&zs[s * 2];
        a0 += v.x;
        a1 += v.y;
    }
    // reduce within the 8-lane group (lane0's chain uses lanes 1/2/4 only)
    a0 += __shfl_down(a0, 4, 64);
    a1 += __shfl_down(a1, 4, 64);
    a0 += __shfl_down(a0, 2, 64);
    a1 += __shfl_down(a1, 2, 64);
    a0 += __shfl_down(a0, 1, 64);
    a1 += __shfl_down(a1, 1, 64);
    if (j == 0) {
        float di = dinv[node];
        float2 zv = *(const float2*)&zs[node * 2];
        float2 o;
        o.x = fmaf(di, a0 + zv.x, b2[0]);
        o.y = fmaf(di, a1 + zv.y, b2[1]);
        *(float2*)&out[node * 2] = o;
    }
}

// ---------------- launch ----------------

extern "C" void kernel_launch(void* const* d_in, const int* in_sizes, int n_in,
                              void* d_out, int out_size, void* d_ws, size_t ws_size,
                              hipStream_t stream) {
    const float* x  = (const float*)d_in[0];
    const int* ei   = (const int*)d_in[1];
    const float* W1 = (const float*)d_in[2];
    const float* b1 = (const float*)d_in[3];
    const float* W2 = (const float*)d_in[4];
    const float* b2 = (const float*)d_in[5];
    float* out = (float*)d_out;

    const int4* src4 = (const int4*)ei;
    const int4* dst4 = (const int4*)(ei + N_EDGES);

    // workspace layout (4-byte units), ~14 MB
    int*      bucket_off = (int*)d_ws;                   // [0, 1024)       783 used
    int*      colsum     = (int*)d_ws + 1024;            // [1024, 2048)
    float*    dinv       = (float*)d_ws + 2048;          // [2048, 52224)
    int*      row_ptr    = (int*)d_ws + 52224;           // 50001 -> pad to 102432
    int*      bhist      = (int*)d_ws + 102432;          // 196*784 = 153664 -> pad 153696
    int*      excT       = (int*)d_ws + 256128;          // 782*200 = 156400 -> pad 156448
    int*      ebin       = (int*)d_ws + 412576;          // 800000 packed ints
    int*      rec        = (int*)d_ws + 1212576;         // 800000 src ints
    _Float16* hs         = (_Float16*)((int*)d_ws + 2012576);  // 50048*64 halves
    float*    zs         = (float*)d_ws + 3614112;       // 100000 floats

    k_hist<<<NBLK, 256, 0, stream>>>(dst4, bhist);
    k_colscan<<<NBUK, 256, 0, stream>>>(bhist, excT, colsum);
    k_binA2s<<<NBLK, 256, 0, stream>>>(src4, dst4, excT, colsum, bucket_off, row_ptr, ebin);
    k_csr_gemm<<<NBUK, 256, 0, stream>>>(ebin, bucket_off, x, W1, row_ptr, dinv, rec, hs);
    k_agg1_l2<<<N_NODES / 16, 256, 0, stream>>>(hs, row_ptr, rec, dinv, b1, W2, zs);
    k_agg2<<<(N_NODES + 31) / 32, 256, 0, stream>>>(zs, row_ptr, rec, dinv, b2, out);
}